// Round 1
// baseline (6978.831 us; speedup 1.0000x reference)
//
#include <hip/hip_runtime.h>
#include <stdint.h>

// ---------------------------------------------------------------------------
// GPS (GINE + dense MHA + MLP, BatchNorm) forward, MI355X round-0 baseline.
// fp32 vector GEMMs, bf16 activation storage, CSR-by-dst for scatter-add,
// BN stats fused into GEMM epilogues, BN applied in consumer prologues.
// ---------------------------------------------------------------------------

#define NN   65536
#define EE   524288
#define DD   256
#define LL   4
#define GG   512
#define NPGx 128
#define HHH  8
#define FFF  512

typedef __attribute__((ext_vector_type(8))) short short8;

__device__ __forceinline__ float b2f(unsigned short u){
  union {unsigned int i; float f;} z; z.i = ((unsigned int)u) << 16; return z.f;
}
__device__ __forceinline__ unsigned short f2b(float f){
  union {float f; unsigned int i;} z; z.f = f;
  unsigned int r = z.i + 0x7fff + ((z.i >> 16) & 1u);
  return (unsigned short)(r >> 16);
}

// ---------------- preprocessing ----------------

// bond_emb (3,8,256): all <=512 possible edge-attr combos -> one table row each
__global__ __launch_bounds__(256) void combo_k(const float* __restrict__ be,
                                               float* __restrict__ tab){
  int c = blockIdx.x, d = threadIdx.x;
  int a0 = c & 7, a1 = (c >> 3) & 7, a2 = (c >> 6) & 7;
  tab[c*DD + d] = be[a0*DD + d] + be[(8 + a1)*DD + d] + be[(16 + a2)*DD + d];
}

__global__ __launch_bounds__(256) void hist_k(const int* __restrict__ ei,
                                              int* __restrict__ cnt){
  for (int i = blockIdx.x*256 + threadIdx.x; i < EE; i += gridDim.x*256)
    atomicAdd(&cnt[ei[EE + i]], 1);
}

// single-block scan: cnt (counts) -> row_ptr (exclusive) and cnt := same prefix
__global__ __launch_bounds__(1024) void scan_k(int* __restrict__ cnt,
                                               int* __restrict__ row_ptr){
  __shared__ int sd[1024];
  __shared__ int carry;
  int t = threadIdx.x;
  if (t == 0) carry = 0;
  __syncthreads();
  for (int base = 0; base < NN; base += 4096){
    int idx = base + t*4;
    int v0 = cnt[idx+0], v1 = cnt[idx+1], v2 = cnt[idx+2], v3 = cnt[idx+3];
    int s = v0 + v1 + v2 + v3;
    sd[t] = s; __syncthreads();
    for (int offd = 1; offd < 1024; offd <<= 1){
      int xv = (t >= offd) ? sd[t - offd] : 0;
      __syncthreads();
      sd[t] += xv;
      __syncthreads();
    }
    int excl = sd[t] - s + carry;
    row_ptr[idx+0] = excl;             cnt[idx+0] = excl;
    row_ptr[idx+1] = excl + v0;        cnt[idx+1] = excl + v0;
    row_ptr[idx+2] = excl + v0 + v1;   cnt[idx+2] = excl + v0 + v1;
    row_ptr[idx+3] = excl + v0+v1+v2;  cnt[idx+3] = excl + v0+v1+v2;
    __syncthreads();
    if (t == 0) carry += sd[1023];
    __syncthreads();
  }
  if (t == 0) row_ptr[NN] = carry;
}

__global__ __launch_bounds__(256) void fill_k(const int* __restrict__ ei,
                                              const int* __restrict__ ea,
                                              int* __restrict__ cursor,
                                              int* __restrict__ slot){
  for (int i = blockIdx.x*256 + threadIdx.x; i < EE; i += gridDim.x*256){
    int s  = ei[i];
    int dn = ei[EE + i];
    int a0 = ea[i*3+0], a1 = ea[i*3+1], a2 = ea[i*3+2];
    int cb = a0 | (a1 << 3) | (a2 << 6);
    int p = atomicAdd(&cursor[dn], 1);
    slot[p] = s | (cb << 16);          // src in [0,65536) fits 16 bits
  }
}

// AtomEncoder + PE fusion: h0 = sum_i atom_emb[i, x[n,i]] + pe @ pe_w + pe_b
__global__ __launch_bounds__(256) void enc_k(const int* __restrict__ x,
                                             const float* __restrict__ pe,
                                             const float* __restrict__ atom_emb,
                                             const float* __restrict__ pe_w,
                                             const float* __restrict__ pe_b,
                                             unsigned short* __restrict__ hb){
  int n = blockIdx.x, d = threadIdx.x;
  __shared__ int xr[9];
  __shared__ float per[20];
  if (d < 9) xr[d] = x[n*9 + d];
  if (d >= 32 && d < 52) per[d-32] = pe[n*20 + (d-32)];
  __syncthreads();
  float acc = pe_b[d];
  #pragma unroll
  for (int i = 0; i < 9; i++) acc += atom_emb[(i*128 + xr[i])*DD + d];
  #pragma unroll
  for (int w = 0; w < 20; w++) acc += per[w] * pe_w[w*DD + d];
  hb[(size_t)n*DD + d] = f2b(acc);
}

// GINE message+aggregate: t1[n] = h[n] + sum_{e->n} relu(h[src_e] + combo[c_e])
__global__ __launch_bounds__(256) void gather_k(const unsigned short* __restrict__ hb,
                                                const int* __restrict__ row_ptr,
                                                const int* __restrict__ slot,
                                                const float* __restrict__ combo,
                                                unsigned short* __restrict__ t1){
  int n = blockIdx.x, d = threadIdx.x;
  int beg = row_ptr[n], end = row_ptr[n+1];
  __shared__ int sl[128];
  float acc = 0.f;
  for (int c0 = beg; c0 < end; c0 += 128){
    int m = end - c0; if (m > 128) m = 128;
    __syncthreads();
    if (d < m) sl[d] = slot[c0 + d];
    __syncthreads();
    for (int j = 0; j < m; j++){
      int s = sl[j];
      int src = s & 0xFFFF;
      int cb  = ((unsigned)s) >> 16;
      float v = b2f(hb[(size_t)src*DD + d]) + combo[cb*DD + d];
      acc += fmaxf(v, 0.f);
    }
  }
  float z = b2f(hb[(size_t)n*DD + d]) + acc;
  t1[(size_t)n*DD + d] = f2b(z);
}

// BatchNorm apply from raw (sum,sumsq) stats
__device__ __forceinline__ float bn_apply(float v, const float* st,
                                          const float* g, const float* b, int k){
  float mu  = st[k] * (1.0f/NN);
  float var = st[DD + k] * (1.0f/NN) - mu*mu;
  float rs  = rsqrtf(var + 1e-5f);
  return (v - mu) * rs * g[k] + b[k];
}

// Generic fused GEMM: C[M,Nn] = prologue(A[M,K]) @ B[K,Nn] + epilogue
// MODE 0: plain A         ; y = acc+bias                 ; stats -> out bf16
// MODE 1: A=relu(bn(A))   ; y = relu(acc+bias)+res       ; stats
// MODE 2: plain A         ; y = acc+bias                 ; no stats (qkv)
// MODE 3: plain A         ; y = acc+bias+res             ; stats (wo)
// MODE 4: A=bn1(A)+bn2(A2); y = relu(acc+bias)           ; no stats (mlp1)
// MODE 5: plain A         ; y = acc+bias                 ; stats (mlp2)
template<int MODE>
__global__ __launch_bounds__(256) void gemm_k(
    const unsigned short* __restrict__ A, const unsigned short* __restrict__ A2,
    const float* __restrict__ B, const float* __restrict__ bias,
    const unsigned short* __restrict__ res,
    const float* __restrict__ stA, const float* __restrict__ gA, const float* __restrict__ bA,
    const float* __restrict__ st2, const float* __restrict__ g2, const float* __restrict__ b2v,
    float* __restrict__ statsOut, unsigned short* __restrict__ C,
    int M, int Nn, int K)
{
  __shared__ float As[16][129];
  __shared__ float Bs[16][129];
  __shared__ float cs[128];
  __shared__ float cq[128];
  int tid  = threadIdx.x;
  int row0 = blockIdx.x * 128;
  int col0 = blockIdx.y * 128;
  int tr = tid >> 4, tc = tid & 15;        // output mapping: rows tr+16i, cols tc+16j
  int ar = tid >> 1, ak = (tid & 1) * 8;   // A-load mapping
  int bk = tid >> 4, bc = (tid & 15) * 8;  // B-load mapping

  float acc[8][8];
  #pragma unroll
  for (int i = 0; i < 8; i++)
    #pragma unroll
    for (int j = 0; j < 8; j++) acc[i][j] = 0.f;

  for (int kt = 0; kt < K; kt += 16){
    float av[8];
    {
      short8 a8 = *(const short8*)(A + (size_t)(row0 + ar)*K + kt + ak);
      #pragma unroll
      for (int u = 0; u < 8; u++) av[u] = b2f((unsigned short)a8[u]);
      if constexpr (MODE == 1){
        #pragma unroll
        for (int u = 0; u < 8; u++){
          int k = kt + ak + u;
          av[u] = fmaxf(bn_apply(av[u], stA, gA, bA, k), 0.f);
        }
      }
      if constexpr (MODE == 4){
        short8 c8 = *(const short8*)(A2 + (size_t)(row0 + ar)*K + kt + ak);
        #pragma unroll
        for (int u = 0; u < 8; u++){
          int k = kt + ak + u;
          av[u] = bn_apply(av[u], stA, gA, bA, k)
                + bn_apply(b2f((unsigned short)c8[u]), st2, g2, b2v, k);
        }
      }
    }
    float bv[8];
    {
      const float* bp = B + (size_t)(kt + bk)*Nn + col0 + bc;
      #pragma unroll
      for (int u = 0; u < 8; u++) bv[u] = bp[u];
    }
    __syncthreads();
    #pragma unroll
    for (int u = 0; u < 8; u++) As[ak + u][ar] = av[u];
    #pragma unroll
    for (int u = 0; u < 8; u++) Bs[bk][bc + u] = bv[u];
    __syncthreads();
    #pragma unroll
    for (int kk = 0; kk < 16; kk++){
      float a[8], b[8];
      #pragma unroll
      for (int i = 0; i < 8; i++) a[i] = As[kk][tr + 16*i];
      #pragma unroll
      for (int j = 0; j < 8; j++) b[j] = Bs[kk][tc + 16*j];
      #pragma unroll
      for (int i = 0; i < 8; i++)
        #pragma unroll
        for (int j = 0; j < 8; j++) acc[i][j] += a[i]*b[j];
    }
  }

  #pragma unroll
  for (int i = 0; i < 8; i++){
    int rowg = row0 + tr + 16*i;
    #pragma unroll
    for (int j = 0; j < 8; j++){
      int colg = col0 + tc + 16*j;
      float y = acc[i][j] + bias[colg];
      if constexpr (MODE == 1) y = fmaxf(y, 0.f) + b2f(res[(size_t)rowg*DD + colg]);
      if constexpr (MODE == 3) y = y + b2f(res[(size_t)rowg*DD + colg]);
      if constexpr (MODE == 4) y = fmaxf(y, 0.f);
      acc[i][j] = y;
      C[(size_t)rowg*Nn + colg] = f2b(y);
    }
  }

  if constexpr (MODE == 0 || MODE == 1 || MODE == 3 || MODE == 5){
    if (tid < 128){ cs[tid] = 0.f; cq[tid] = 0.f; }
    __syncthreads();
    #pragma unroll
    for (int j = 0; j < 8; j++){
      float ps = 0.f, pq = 0.f;
      #pragma unroll
      for (int i = 0; i < 8; i++){ float v = acc[i][j]; ps += v; pq += v*v; }
      ps += __shfl_xor(ps, 16, 64); pq += __shfl_xor(pq, 16, 64);
      ps += __shfl_xor(ps, 32, 64); pq += __shfl_xor(pq, 32, 64);
      if ((tid & 63) < 16){
        atomicAdd(&cs[tc + 16*j], ps);
        atomicAdd(&cq[tc + 16*j], pq);
      }
    }
    __syncthreads();
    if (tid < 128){
      atomicAdd(&statsOut[col0 + tid],      cs[tid]);
      atomicAdd(&statsOut[DD + col0 + tid], cq[tid]);
    }
  }
}

// per-(graph,head) online-softmax attention; qkv bf16 [N,768] -> o bf16 [N,256]
__global__ __launch_bounds__(128) void attn_k(const unsigned short* __restrict__ qkv,
                                              unsigned short* __restrict__ o_out){
  int g  = blockIdx.x >> 3;
  int hh = blockIdx.x & 7;
  int t  = threadIdx.x;                 // row m = t
  __shared__ float ks[128][33];
  __shared__ float vs[128][33];
  size_t base = (size_t)(g*NPGx + t)*768 + hh*32;
  float q[32];
  {
    const short8* p = (const short8*)(qkv + base);
    #pragma unroll
    for (int c = 0; c < 4; c++){
      short8 v = p[c];
      #pragma unroll
      for (int j = 0; j < 8; j++) q[c*8 + j] = b2f((unsigned short)v[j]);
    }
  }
  {
    const short8* pk = (const short8*)(qkv + base + 256);
    const short8* pv = (const short8*)(qkv + base + 512);
    #pragma unroll
    for (int c = 0; c < 4; c++){
      short8 kv = pk[c], vv = pv[c];
      #pragma unroll
      for (int j = 0; j < 8; j++){
        ks[t][c*8 + j] = b2f((unsigned short)kv[j]);
        vs[t][c*8 + j] = b2f((unsigned short)vv[j]);
      }
    }
  }
  __syncthreads();
  float mrun = -3.0e38f, lsum = 0.f;
  float o[32];
  #pragma unroll
  for (int j = 0; j < 32; j++) o[j] = 0.f;
  for (int u = 0; u < 128; u++){
    float s0 = 0.f, s1 = 0.f, s2 = 0.f, s3 = 0.f;
    #pragma unroll
    for (int j = 0; j < 32; j += 4){
      s0 += q[j+0]*ks[u][j+0];
      s1 += q[j+1]*ks[u][j+1];
      s2 += q[j+2]*ks[u][j+2];
      s3 += q[j+3]*ks[u][j+3];
    }
    float s = ((s0+s1)+(s2+s3)) * 0.17677669529663687f;   // 1/sqrt(32)
    float mnew = fmaxf(mrun, s);
    float corr = __expf(mrun - mnew);
    float p    = __expf(s - mnew);
    lsum = lsum*corr + p;
    #pragma unroll
    for (int j = 0; j < 32; j++) o[j] = o[j]*corr + p*vs[u][j];
    mrun = mnew;
  }
  float inv = 1.f / lsum;
  unsigned short* dst = o_out + (size_t)(g*NPGx + t)*DD + hh*32;
  #pragma unroll
  for (int j = 0; j < 32; j++) dst[j] = f2b(o[j]*inv);
}

// in-place BN finalize on h (pre-BN -> post-BN)
__global__ __launch_bounds__(256) void bnf_k(unsigned short* __restrict__ hb,
                                             const float* __restrict__ st,
                                             const float* __restrict__ g,
                                             const float* __restrict__ b){
  int n = blockIdx.x, d = threadIdx.x;
  size_t i = (size_t)n*DD + d;
  hb[i] = f2b(bn_apply(b2f(hb[i]), st, g, b, d));
}

// global_add_pool over contiguous equal-size graphs
__global__ __launch_bounds__(256) void pool_k(const unsigned short* __restrict__ hb,
                                              float* __restrict__ out){
  int g = blockIdx.x, d = threadIdx.x;
  float acc = 0.f;
  for (int r = 0; r < NPGx; r++) acc += b2f(hb[(size_t)(g*NPGx + r)*DD + d]);
  out[g*DD + d] = acc;
}

// ---------------------------------------------------------------------------

extern "C" void kernel_launch(void* const* d_in, const int* in_sizes, int n_in,
                              void* d_out, int out_size, void* d_ws, size_t ws_size,
                              hipStream_t stream)
{
  const int*   x         = (const int*)  d_in[0];
  const int*   ei        = (const int*)  d_in[1];
  const int*   ea        = (const int*)  d_in[2];
  const float* pe        = (const float*)d_in[4];
  const float* atom_emb  = (const float*)d_in[5];
  const float* bond_emb  = (const float*)d_in[6];
  const float* pe_w      = (const float*)d_in[7];
  const float* pe_b      = (const float*)d_in[8];
  const float* gine_w1   = (const float*)d_in[9];
  const float* gine_b1   = (const float*)d_in[10];
  const float* gine_g1   = (const float*)d_in[11];
  const float* gine_be1  = (const float*)d_in[12];
  const float* gine_w2   = (const float*)d_in[13];
  const float* gine_b2   = (const float*)d_in[14];
  const float* attn_wqkv = (const float*)d_in[15];
  const float* attn_bqkv = (const float*)d_in[16];
  const float* attn_wo   = (const float*)d_in[17];
  const float* attn_bo   = (const float*)d_in[18];
  const float* n1_g      = (const float*)d_in[19];
  const float* n1_b      = (const float*)d_in[20];
  const float* n2_g      = (const float*)d_in[21];
  const float* n2_b      = (const float*)d_in[22];
  const float* n3_g      = (const float*)d_in[23];
  const float* n3_b      = (const float*)d_in[24];
  const float* mlp_w1    = (const float*)d_in[25];
  const float* mlp_b1    = (const float*)d_in[26];
  const float* mlp_w2    = (const float*)d_in[27];
  const float* mlp_b2    = (const float*)d_in[28];
  float* out = (float*)d_out;

  char* wsp = (char*)d_ws;
  size_t off = 0;
  auto alloc = [&](size_t bytes)->void*{
    void* p = wsp + off; off += (bytes + 255) & ~(size_t)255; return p;
  };
  unsigned short* hb  = (unsigned short*)alloc((size_t)NN*DD*2);   // current h
  unsigned short* t1  = (unsigned short*)alloc((size_t)NN*DD*2);
  unsigned short* t2  = (unsigned short*)alloc((size_t)NN*DD*2);
  unsigned short* t4  = (unsigned short*)alloc((size_t)NN*DD*2);
  unsigned short* big = (unsigned short*)alloc((size_t)NN*768*2);  // qkv / mlp hidden
  float* combo   = (float*)alloc((size_t)512*DD*4);
  int*   row_ptr = (int*)  alloc((size_t)(NN+1)*4);
  int*   cursor  = (int*)  alloc((size_t)NN*4);
  int*   slot    = (int*)  alloc((size_t)EE*4);
  float* stats   = (float*)alloc((size_t)LL*4*2*DD*4);
  if (off > ws_size) return;   // workspace too small: fail visibly (zeros)

  hipMemsetAsync(stats,  0, (size_t)LL*4*2*DD*4, stream);
  hipMemsetAsync(cursor, 0, (size_t)NN*4, stream);
  combo_k<<<512, 256, 0, stream>>>(bond_emb, combo);
  hist_k <<<512, 256, 0, stream>>>(ei, cursor);
  scan_k <<<1, 1024, 0, stream>>>(cursor, row_ptr);
  fill_k <<<512, 256, 0, stream>>>(ei, ea, cursor, slot);
  enc_k  <<<NN, 256, 0, stream>>>(x, pe, atom_emb, pe_w, pe_b, hb);

  for (int l = 0; l < LL; l++){
    const float* w1   = gine_w1   + (size_t)l*DD*DD;
    const float* b1   = gine_b1   + l*DD;
    const float* g1   = gine_g1   + l*DD;
    const float* be1  = gine_be1  + l*DD;
    const float* w2   = gine_w2   + (size_t)l*DD*DD;
    const float* b2   = gine_b2   + l*DD;
    const float* wqkv = attn_wqkv + (size_t)l*DD*768;
    const float* bqkv = attn_bqkv + l*768;
    const float* wo   = attn_wo   + (size_t)l*DD*DD;
    const float* bo   = attn_bo   + l*DD;
    const float* mw1  = mlp_w1    + (size_t)l*DD*FFF;
    const float* mb1  = mlp_b1    + l*FFF;
    const float* mw2  = mlp_w2    + (size_t)l*FFF*DD;
    const float* mb2  = mlp_b2    + l*DD;
    float* S0 = stats + (l*4+0)*2*DD;
    float* S1 = stats + (l*4+1)*2*DD;
    float* S2 = stats + (l*4+2)*2*DD;
    float* S3 = stats + (l*4+3)*2*DD;

    gather_k<<<NN, 256, 0, stream>>>(hb, row_ptr, slot, combo, t1);
    gemm_k<0><<<dim3(NN/128, 2), 256, 0, stream>>>(t1, nullptr, w1, b1, nullptr,
        nullptr, nullptr, nullptr, nullptr, nullptr, nullptr, S0, t2, NN, DD, DD);
    gemm_k<1><<<dim3(NN/128, 2), 256, 0, stream>>>(t2, nullptr, w2, b2, hb,
        S0, g1, be1, nullptr, nullptr, nullptr, S1, t1, NN, DD, DD);
    gemm_k<2><<<dim3(NN/128, 6), 256, 0, stream>>>(hb, nullptr, wqkv, bqkv, nullptr,
        nullptr, nullptr, nullptr, nullptr, nullptr, nullptr, nullptr, big, NN, 768, DD);
    attn_k<<<GG*HHH, 128, 0, stream>>>(big, t2);
    gemm_k<3><<<dim3(NN/128, 2), 256, 0, stream>>>(t2, nullptr, wo, bo, hb,
        nullptr, nullptr, nullptr, nullptr, nullptr, nullptr, S2, t4, NN, DD, DD);
    gemm_k<4><<<dim3(NN/128, 4), 256, 0, stream>>>(t1, t4, mw1, mb1, nullptr,
        S1, n1_g + l*DD, n1_b + l*DD, S2, n2_g + l*DD, n2_b + l*DD, nullptr,
        big, NN, FFF, DD);
    gemm_k<5><<<dim3(NN/128, 2), 256, 0, stream>>>(big, nullptr, mw2, mb2, nullptr,
        nullptr, nullptr, nullptr, nullptr, nullptr, nullptr, S3, hb, NN, DD, FFF);
    bnf_k<<<NN, 256, 0, stream>>>(hb, S3, n3_g + l*DD, n3_b + l*DD);
  }
  pool_k<<<GG, 256, 0, stream>>>(hb, out);
}

// Round 2
// 3042.014 us; speedup vs baseline: 2.2941x; 2.2941x over previous
//
#include <hip/hip_runtime.h>
#include <stdint.h>

// ---------------------------------------------------------------------------
// GPS (GINE + dense MHA + MLP, BatchNorm) forward, MI355X round-2.
// All GEMMs on MFMA (16x16x32 bf16, m97 structure: 128x128 tile, 4 waves,
// global_load_lds width-16 staging, 2-barrier K-loop). BN folded into
// elementwise passes + GEMM epilogues. CSR gather wave-per-node.
// ---------------------------------------------------------------------------

#define NN   65536
#define EE   524288
#define DD   256
#define LL   4
#define GG   512
#define NPGx 128
#define FFF  512

typedef __attribute__((ext_vector_type(8))) short short8;
typedef __attribute__((ext_vector_type(8))) __bf16 bf16x8;
typedef __attribute__((ext_vector_type(4))) float f32x4;

__device__ __forceinline__ float b2f(unsigned short u){
  union {unsigned int i; float f;} z; z.i = ((unsigned int)u) << 16; return z.f;
}
__device__ __forceinline__ unsigned short f2b(float f){
  union {float f; unsigned int i;} z; z.f = f;
  unsigned int r = z.i + 0x7fff + ((z.i >> 16) & 1u);
  return (unsigned short)(r >> 16);
}

__device__ __forceinline__ void gld16(void* lds, const void* g){
  __builtin_amdgcn_global_load_lds(
      (const __attribute__((address_space(1))) void*)g,
      (__attribute__((address_space(3))) void*)lds, 16, 0, 0);
}

// ---------------- preprocessing ----------------

// bond_emb (3,8,256): all 512 edge-attr combos -> bf16 table rows
__global__ __launch_bounds__(256) void combo_k(const float* __restrict__ be,
                                               unsigned short* __restrict__ tab){
  int c = blockIdx.x, d = threadIdx.x;
  int a0 = c & 7, a1 = (c >> 3) & 7, a2 = (c >> 6) & 7;
  tab[c*DD + d] = f2b(be[a0*DD + d] + be[(8 + a1)*DD + d] + be[(16 + a2)*DD + d]);
}

__global__ __launch_bounds__(256) void hist_k(const int* __restrict__ ei,
                                              int* __restrict__ cnt){
  for (int i = blockIdx.x*256 + threadIdx.x; i < EE; i += gridDim.x*256)
    atomicAdd(&cnt[ei[EE + i]], 1);
}

__global__ __launch_bounds__(1024) void scan_k(int* __restrict__ cnt,
                                               int* __restrict__ row_ptr){
  __shared__ int sd[1024];
  __shared__ int carry;
  int t = threadIdx.x;
  if (t == 0) carry = 0;
  __syncthreads();
  for (int base = 0; base < NN; base += 4096){
    int idx = base + t*4;
    int v0 = cnt[idx+0], v1 = cnt[idx+1], v2 = cnt[idx+2], v3 = cnt[idx+3];
    int s = v0 + v1 + v2 + v3;
    sd[t] = s; __syncthreads();
    for (int offd = 1; offd < 1024; offd <<= 1){
      int xv = (t >= offd) ? sd[t - offd] : 0;
      __syncthreads();
      sd[t] += xv;
      __syncthreads();
    }
    int excl = sd[t] - s + carry;
    row_ptr[idx+0] = excl;             cnt[idx+0] = excl;
    row_ptr[idx+1] = excl + v0;        cnt[idx+1] = excl + v0;
    row_ptr[idx+2] = excl + v0 + v1;   cnt[idx+2] = excl + v0 + v1;
    row_ptr[idx+3] = excl + v0+v1+v2;  cnt[idx+3] = excl + v0+v1+v2;
    __syncthreads();
    if (t == 0) carry += sd[1023];
    __syncthreads();
  }
  if (t == 0) row_ptr[NN] = carry;
}

__global__ __launch_bounds__(256) void fill_k(const int* __restrict__ ei,
                                              const int* __restrict__ ea,
                                              int* __restrict__ cursor,
                                              int* __restrict__ slot){
  for (int i = blockIdx.x*256 + threadIdx.x; i < EE; i += gridDim.x*256){
    int s  = ei[i];
    int dn = ei[EE + i];
    int a0 = ea[i*3+0], a1 = ea[i*3+1], a2 = ea[i*3+2];
    int cb = a0 | (a1 << 3) | (a2 << 6);
    int p = atomicAdd(&cursor[dn], 1);
    slot[p] = s | (cb << 16);
  }
}

// weight transpose + bf16: dst[n*K+k] = src[k*Nsrc+n], for all 6 mats x 4 layers
__global__ __launch_bounds__(256) void twt_k(const float* __restrict__ w1,
                                             const float* __restrict__ w2,
                                             const float* __restrict__ wqkv,
                                             const float* __restrict__ wo,
                                             const float* __restrict__ m1,
                                             const float* __restrict__ m2,
                                             unsigned short* __restrict__ wt){
  int l = blockIdx.x / 2304;
  int r = blockIdx.x % 2304;
  const float* src; unsigned short* dst; int K, Nsrc, n;
  unsigned short* wl = wt + (size_t)l*655360;
  if (r < 256)      { src = w1  +(size_t)l*65536;  dst = wl;          K=256; Nsrc=256; n=r; }
  else if (r < 512) { src = w2  +(size_t)l*65536;  dst = wl+65536;    K=256; Nsrc=256; n=r-256; }
  else if (r < 1280){ src = wqkv+(size_t)l*196608; dst = wl+131072;   K=256; Nsrc=768; n=r-512; }
  else if (r < 1536){ src = wo  +(size_t)l*65536;  dst = wl+327680;   K=256; Nsrc=256; n=r-1280; }
  else if (r < 2048){ src = m1  +(size_t)l*131072; dst = wl+393216;   K=256; Nsrc=512; n=r-1536; }
  else              { src = m2  +(size_t)l*131072; dst = wl+524288;   K=512; Nsrc=256; n=r-2048; }
  for (int k = threadIdx.x; k < K; k += 256)
    dst[(size_t)n*K + k] = f2b(src[(size_t)k*Nsrc + n]);
}

// AtomEncoder + PE fusion
__global__ __launch_bounds__(256) void enc_k(const int* __restrict__ x,
                                             const float* __restrict__ pe,
                                             const float* __restrict__ atom_emb,
                                             const float* __restrict__ pe_w,
                                             const float* __restrict__ pe_b,
                                             unsigned short* __restrict__ hb){
  int n = blockIdx.x, d = threadIdx.x;
  __shared__ int xr[9];
  __shared__ float per[20];
  if (d < 9) xr[d] = x[n*9 + d];
  if (d >= 32 && d < 52) per[d-32] = pe[n*20 + (d-32)];
  __syncthreads();
  float acc = pe_b[d];
  #pragma unroll
  for (int i = 0; i < 9; i++) acc += atom_emb[(i*128 + xr[i])*DD + d];
  #pragma unroll
  for (int w = 0; w < 20; w++) acc += per[w] * pe_w[w*DD + d];
  hb[(size_t)n*DD + d] = f2b(acc);
}

// GINE gather: wave-per-node, 4 bf16 per lane (8B loads)
__global__ __launch_bounds__(256) void gather_k(const unsigned short* __restrict__ hb,
                                                const int* __restrict__ row_ptr,
                                                const int* __restrict__ slot,
                                                const unsigned short* __restrict__ combo,
                                                unsigned short* __restrict__ t1){
  int w = threadIdx.x >> 6, lane = threadIdx.x & 63;
  int n = blockIdx.x*4 + w;
  int beg = row_ptr[n], end = row_ptr[n+1];
  int d0 = lane*4;
  float a0 = 0.f, a1 = 0.f, a2 = 0.f, a3 = 0.f;
  for (int e = beg; e < end; e++){
    int s = slot[e];
    int src = s & 0xFFFF;
    int cb  = ((unsigned)s) >> 16;
    ushort4 hv = *(const ushort4*)(hb + (size_t)src*DD + d0);
    ushort4 cv = *(const ushort4*)(combo + (size_t)cb*DD + d0);
    a0 += fmaxf(b2f(hv.x)+b2f(cv.x), 0.f);
    a1 += fmaxf(b2f(hv.y)+b2f(cv.y), 0.f);
    a2 += fmaxf(b2f(hv.z)+b2f(cv.z), 0.f);
    a3 += fmaxf(b2f(hv.w)+b2f(cv.w), 0.f);
  }
  ushort4 hn = *(const ushort4*)(hb + (size_t)n*DD + d0);
  ushort4 o;
  o.x = f2b(b2f(hn.x)+a0); o.y = f2b(b2f(hn.y)+a1);
  o.z = f2b(b2f(hn.z)+a2); o.w = f2b(b2f(hn.w)+a3);
  *(ushort4*)(t1 + (size_t)n*DD + d0) = o;
}

// ---------------- MFMA GEMM ----------------
// C[M,Nn] = epi(A[M,K] @ Bt[Nn,K]^T + bias); 128x128 tile, 4 waves (2x2),
// each wave 4x4 frags of 16x16x32. Bt is the transposed bf16 weight.
template<bool RELU, bool RES, bool STATS>
__global__ __launch_bounds__(256) void mgemm_k(
    const unsigned short* __restrict__ A,
    const unsigned short* __restrict__ Bt,
    const float* __restrict__ bias,
    const unsigned short* __restrict__ res,
    float* __restrict__ statsOut,
    unsigned short* __restrict__ C,
    int Nn, int K)
{
  __shared__ __align__(16) __bf16 As[4096];   // [128][32]
  __shared__ __align__(16) __bf16 Bs[4096];   // [128][32]
  __shared__ float cs[128];
  __shared__ float cq[128];
  int tid  = threadIdx.x;
  int wid  = tid >> 6, lane = tid & 63;
  int row0 = blockIdx.x * 128, col0 = blockIdx.y * 128;
  int wr = wid >> 1, wc = wid & 1;
  int lr = lane >> 2, lc = (lane & 3) * 8;   // staging: 4 lanes/row, 16B each
  int fr = lane & 15, fq = lane >> 4;        // frag: row/col = fr, kgroup = fq

  if (STATS && tid < 128){ cs[tid] = 0.f; cq[tid] = 0.f; }

  f32x4 acc[4][4];
  #pragma unroll
  for (int i = 0; i < 4; i++)
    #pragma unroll
    for (int j = 0; j < 4; j++) acc[i][j] = f32x4{0.f, 0.f, 0.f, 0.f};

  const unsigned short* ga0 = A  + (size_t)(row0 + 16*wid     + lr)*K + lc;
  const unsigned short* ga1 = A  + (size_t)(row0 + 16*(wid+4) + lr)*K + lc;
  const unsigned short* gb0 = Bt + (size_t)(col0 + 16*wid     + lr)*K + lc;
  const unsigned short* gb1 = Bt + (size_t)(col0 + 16*(wid+4) + lr)*K + lc;

  for (int kt = 0; kt < K; kt += 32){
    __syncthreads();                         // previous tile consumed
    gld16(&As[wid*512],     ga0 + kt);       // wave-uniform LDS base + lane*16
    gld16(&As[(wid+4)*512], ga1 + kt);
    gld16(&Bs[wid*512],     gb0 + kt);
    gld16(&Bs[(wid+4)*512], gb1 + kt);
    __syncthreads();                         // compiler drains vmcnt before barrier
    bf16x8 a[4], b[4];
    #pragma unroll
    for (int i = 0; i < 4; i++)
      a[i] = *(const bf16x8*)&As[(wr*64 + 16*i + fr)*32 + fq*8];
    #pragma unroll
    for (int j = 0; j < 4; j++)
      b[j] = *(const bf16x8*)&Bs[(wc*64 + 16*j + fr)*32 + fq*8];
    #pragma unroll
    for (int i = 0; i < 4; i++)
      #pragma unroll
      for (int j = 0; j < 4; j++)
        acc[i][j] = __builtin_amdgcn_mfma_f32_16x16x32_bf16(a[i], b[j], acc[i][j], 0, 0, 0);
  }

  float bj[4];
  #pragma unroll
  for (int j = 0; j < 4; j++) bj[j] = bias[col0 + wc*64 + 16*j + fr];

  #pragma unroll
  for (int i = 0; i < 4; i++){
    #pragma unroll
    for (int j = 0; j < 4; j++){
      int col = col0 + wc*64 + 16*j + fr;
      #pragma unroll
      for (int r = 0; r < 4; r++){
        int row = row0 + wr*64 + 16*i + fq*4 + r;       // m89-verified C/D map
        float y = acc[i][j][r] + bj[j];
        if constexpr (RELU) y = fmaxf(y, 0.f);
        if constexpr (RES)  y += b2f(res[(size_t)row*Nn + col]);
        acc[i][j][r] = y;
        C[(size_t)row*Nn + col] = f2b(y);
      }
    }
  }

  if constexpr (STATS){
    #pragma unroll
    for (int j = 0; j < 4; j++){
      float ps = 0.f, pq = 0.f;
      #pragma unroll
      for (int i = 0; i < 4; i++)
        #pragma unroll
        for (int r = 0; r < 4; r++){ float v = acc[i][j][r]; ps += v; pq += v*v; }
      ps += __shfl_xor(ps, 16, 64); pq += __shfl_xor(pq, 16, 64);
      ps += __shfl_xor(ps, 32, 64); pq += __shfl_xor(pq, 32, 64);
      if (lane < 16){
        atomicAdd(&cs[wc*64 + 16*j + fr], ps);
        atomicAdd(&cq[wc*64 + 16*j + fr], pq);
      }
    }
    __syncthreads();
    if (tid < 128){
      atomicAdd(&statsOut[col0 + tid],       cs[tid]);
      atomicAdd(&statsOut[256 + col0 + tid], cq[tid]);
    }
  }
}

// in-place BN (+optional relu) elementwise, 8 bf16/thread
template<bool RELU>
__global__ __launch_bounds__(256) void bnap_k(unsigned short* __restrict__ t,
                                              const float* __restrict__ st,
                                              const float* __restrict__ g,
                                              const float* __restrict__ b){
  __shared__ float sc[256], sh[256];
  int tid = threadIdx.x;
  {
    float mu  = st[tid] * (1.f/NN);
    float var = st[256+tid] * (1.f/NN) - mu*mu;
    float s   = rsqrtf(var + 1e-5f) * g[tid];
    sc[tid] = s; sh[tid] = b[tid] - mu*s;
  }
  __syncthreads();
  size_t base = ((size_t)blockIdx.x*256 + tid)*8;
  int c0 = (int)(base & 255);
  short8 v = *(const short8*)(t + base);
  short8 o;
  #pragma unroll
  for (int u = 0; u < 8; u++){
    float f = b2f((unsigned short)v[u])*sc[c0+u] + sh[c0+u];
    if constexpr (RELU) f = fmaxf(f, 0.f);
    o[u] = (short)f2b(f);
  }
  *(short8*)(t + base) = o;
}

// X = bn(t1;S1,n1) + bn(t4;S2,n2)  (mlp input; both BNs are linear, no relu)
__global__ __launch_bounds__(256) void combine_k(
    const unsigned short* __restrict__ t1, const unsigned short* __restrict__ t4,
    const float* __restrict__ S1, const float* __restrict__ g1, const float* __restrict__ b1,
    const float* __restrict__ S2, const float* __restrict__ g2, const float* __restrict__ b2,
    unsigned short* __restrict__ X)
{
  __shared__ float sc1[256], sh1[256], sc2[256], sh2[256];
  int tid = threadIdx.x;
  {
    float mu1 = S1[tid]*(1.f/NN), va1 = S1[256+tid]*(1.f/NN) - mu1*mu1;
    float s1 = rsqrtf(va1+1e-5f)*g1[tid]; sc1[tid]=s1; sh1[tid]=b1[tid]-mu1*s1;
    float mu2 = S2[tid]*(1.f/NN), va2 = S2[256+tid]*(1.f/NN) - mu2*mu2;
    float s2 = rsqrtf(va2+1e-5f)*g2[tid]; sc2[tid]=s2; sh2[tid]=b2[tid]-mu2*s2;
  }
  __syncthreads();
  size_t base = ((size_t)blockIdx.x*256 + tid)*8;
  int c0 = (int)(base & 255);
  short8 v1 = *(const short8*)(t1 + base);
  short8 v4 = *(const short8*)(t4 + base);
  short8 o;
  #pragma unroll
  for (int u = 0; u < 8; u++){
    float f = b2f((unsigned short)v1[u])*sc1[c0+u] + sh1[c0+u]
            + b2f((unsigned short)v4[u])*sc2[c0+u] + sh2[c0+u];
    o[u] = (short)f2b(f);
  }
  *(short8*)(X + base) = o;
}

// per-(graph,head) online-softmax attention; qkv bf16 [N,768] -> o bf16 [N,256]
__global__ __launch_bounds__(128) void attn_k(const unsigned short* __restrict__ qkv,
                                              unsigned short* __restrict__ o_out){
  int g  = blockIdx.x >> 3;
  int hh = blockIdx.x & 7;
  int t  = threadIdx.x;
  __shared__ float ks[128][33];
  __shared__ float vs[128][33];
  size_t base = (size_t)(g*NPGx + t)*768 + hh*32;
  float q[32];
  {
    const short8* p = (const short8*)(qkv + base);
    #pragma unroll
    for (int c = 0; c < 4; c++){
      short8 v = p[c];
      #pragma unroll
      for (int j = 0; j < 8; j++) q[c*8 + j] = b2f((unsigned short)v[j]);
    }
  }
  {
    const short8* pk = (const short8*)(qkv + base + 256);
    const short8* pv = (const short8*)(qkv + base + 512);
    #pragma unroll
    for (int c = 0; c < 4; c++){
      short8 kv = pk[c], vv = pv[c];
      #pragma unroll
      for (int j = 0; j < 8; j++){
        ks[t][c*8 + j] = b2f((unsigned short)kv[j]);
        vs[t][c*8 + j] = b2f((unsigned short)vv[j]);
      }
    }
  }
  __syncthreads();
  float mrun = -3.0e38f, lsum = 0.f;
  float o[32];
  #pragma unroll
  for (int j = 0; j < 32; j++) o[j] = 0.f;
  for (int u = 0; u < 128; u++){
    float s0 = 0.f, s1 = 0.f, s2 = 0.f, s3 = 0.f;
    #pragma unroll
    for (int j = 0; j < 32; j += 4){
      s0 += q[j+0]*ks[u][j+0];
      s1 += q[j+1]*ks[u][j+1];
      s2 += q[j+2]*ks[u][j+2];
      s3 += q[j+3]*ks[u][j+3];
    }
    float s = ((s0+s1)+(s2+s3)) * 0.17677669529663687f;
    float mnew = fmaxf(mrun, s);
    float corr = __expf(mrun - mnew);
    float p    = __expf(s - mnew);
    lsum = lsum*corr + p;
    #pragma unroll
    for (int j = 0; j < 32; j++) o[j] = o[j]*corr + p*vs[u][j];
    mrun = mnew;
  }
  float inv = 1.f / lsum;
  unsigned short* dst = o_out + (size_t)(g*NPGx + t)*DD + hh*32;
  #pragma unroll
  for (int j = 0; j < 32; j++) dst[j] = f2b(o[j]*inv);
}

// global_add_pool
__global__ __launch_bounds__(256) void pool_k(const unsigned short* __restrict__ hb,
                                              float* __restrict__ out){
  int g = blockIdx.x, d = threadIdx.x;
  float acc = 0.f;
  for (int r = 0; r < NPGx; r++) acc += b2f(hb[(size_t)(g*NPGx + r)*DD + d]);
  out[g*DD + d] = acc;
}

// ---------------------------------------------------------------------------

extern "C" void kernel_launch(void* const* d_in, const int* in_sizes, int n_in,
                              void* d_out, int out_size, void* d_ws, size_t ws_size,
                              hipStream_t stream)
{
  const int*   x         = (const int*)  d_in[0];
  const int*   ei        = (const int*)  d_in[1];
  const int*   ea        = (const int*)  d_in[2];
  const float* pe        = (const float*)d_in[4];
  const float* atom_emb  = (const float*)d_in[5];
  const float* bond_emb  = (const float*)d_in[6];
  const float* pe_w      = (const float*)d_in[7];
  const float* pe_b      = (const float*)d_in[8];
  const float* gine_w1   = (const float*)d_in[9];
  const float* gine_b1   = (const float*)d_in[10];
  const float* gine_g1   = (const float*)d_in[11];
  const float* gine_be1  = (const float*)d_in[12];
  const float* gine_w2   = (const float*)d_in[13];
  const float* gine_b2   = (const float*)d_in[14];
  const float* attn_wqkv = (const float*)d_in[15];
  const float* attn_bqkv = (const float*)d_in[16];
  const float* attn_wo   = (const float*)d_in[17];
  const float* attn_bo   = (const float*)d_in[18];
  const float* n1_g      = (const float*)d_in[19];
  const float* n1_b      = (const float*)d_in[20];
  const float* n2_g      = (const float*)d_in[21];
  const float* n2_b      = (const float*)d_in[22];
  const float* n3_g      = (const float*)d_in[23];
  const float* n3_b      = (const float*)d_in[24];
  const float* mlp_w1    = (const float*)d_in[25];
  const float* mlp_b1    = (const float*)d_in[26];
  const float* mlp_w2    = (const float*)d_in[27];
  const float* mlp_b2    = (const float*)d_in[28];
  float* out = (float*)d_out;

  char* wsp = (char*)d_ws;
  size_t off = 0;
  auto alloc = [&](size_t bytes)->void*{
    void* p = wsp + off; off += (bytes + 255) & ~(size_t)255; return p;
  };
  unsigned short* hb  = (unsigned short*)alloc((size_t)NN*DD*2);
  unsigned short* t1  = (unsigned short*)alloc((size_t)NN*DD*2);
  unsigned short* t2  = (unsigned short*)alloc((size_t)NN*DD*2);
  unsigned short* t4  = (unsigned short*)alloc((size_t)NN*DD*2);
  unsigned short* big = (unsigned short*)alloc((size_t)NN*768*2);  // qkv / mlp hidden
  unsigned short* wt  = (unsigned short*)alloc((size_t)LL*655360*2);
  unsigned short* combo = (unsigned short*)alloc((size_t)512*DD*2);
  int*   row_ptr = (int*)  alloc((size_t)(NN+1)*4);
  int*   cursor  = (int*)  alloc((size_t)NN*4);
  int*   slot    = (int*)  alloc((size_t)EE*4);
  float* stats   = (float*)alloc((size_t)LL*4*2*DD*4);
  if (off > ws_size) return;

  hipMemsetAsync(stats,  0, (size_t)LL*4*2*DD*4, stream);
  hipMemsetAsync(cursor, 0, (size_t)NN*4, stream);
  combo_k<<<512, 256, 0, stream>>>(bond_emb, combo);
  twt_k  <<<LL*2304, 256, 0, stream>>>(gine_w1, gine_w2, attn_wqkv, attn_wo,
                                       mlp_w1, mlp_w2, wt);
  hist_k <<<512, 256, 0, stream>>>(ei, cursor);
  scan_k <<<1, 1024, 0, stream>>>(cursor, row_ptr);
  fill_k <<<512, 256, 0, stream>>>(ei, ea, cursor, slot);
  enc_k  <<<NN, 256, 0, stream>>>(x, pe, atom_emb, pe_w, pe_b, hb);

  for (int l = 0; l < LL; l++){
    unsigned short* wl = wt + (size_t)l*655360;
    const float* b1   = gine_b1   + l*DD;
    const float* b2   = gine_b2   + l*DD;
    const float* bqkv = attn_bqkv + l*768;
    const float* bo   = attn_bo   + l*DD;
    const float* mb1  = mlp_b1    + l*FFF;
    const float* mb2  = mlp_b2    + l*DD;
    float* S0 = stats + (l*4+0)*2*DD;
    float* S1 = stats + (l*4+1)*2*DD;
    float* S2 = stats + (l*4+2)*2*DD;
    float* S3 = stats + (l*4+3)*2*DD;

    gather_k<<<NN/4, 256, 0, stream>>>(hb, row_ptr, slot, combo, t1);
    // t2 = t1 @ w1 + b1 ; stats S0
    mgemm_k<false,false,true><<<dim3(NN/128, 2), 256, 0, stream>>>(
        t1, wl + 0, b1, nullptr, S0, t2, 256, 256);
    // t2 = relu(bn(t2; S0, g1, be1))
    bnap_k<true><<<NN*DD/2048, 256, 0, stream>>>(t2, S0, gine_g1 + l*DD, gine_be1 + l*DD);
    // t1 = relu(t2 @ w2 + b2) + hb ; stats S1
    mgemm_k<true,true,true><<<dim3(NN/128, 2), 256, 0, stream>>>(
        t2, wl + 65536, b2, hb, S1, t1, 256, 256);
    // big = hb @ wqkv + bqkv
    mgemm_k<false,false,false><<<dim3(NN/128, 6), 256, 0, stream>>>(
        hb, wl + 131072, bqkv, nullptr, nullptr, big, 768, 256);
    attn_k<<<GG*8, 128, 0, stream>>>(big, t2);
    // t4 = t2 @ wo + bo + hb ; stats S2
    mgemm_k<false,true,true><<<dim3(NN/128, 2), 256, 0, stream>>>(
        t2, wl + 327680, bo, hb, S2, t4, 256, 256);
    // t2 = bn(t1;S1,n1) + bn(t4;S2,n2)
    combine_k<<<NN*DD/2048, 256, 0, stream>>>(
        t1, t4, S1, n1_g + l*DD, n1_b + l*DD, S2, n2_g + l*DD, n2_b + l*DD, t2);
    // big = relu(t2 @ mw1 + mb1)
    mgemm_k<true,false,false><<<dim3(NN/128, 4), 256, 0, stream>>>(
        t2, wl + 393216, mb1, nullptr, nullptr, big, 512, 256);
    // hb = big @ mw2 + mb2 ; stats S3
    mgemm_k<false,false,true><<<dim3(NN/128, 2), 256, 0, stream>>>(
        big, wl + 524288, mb2, nullptr, S3, hb, 256, 512);
    // hb = bn(hb; S3, n3)
    bnap_k<false><<<NN*DD/2048, 256, 0, stream>>>(hb, S3, n3_g + l*DD, n3_b + l*DD);
  }
  pool_k<<<GG, 256, 0, stream>>>(hb, out);
}

// Round 3
// 2128.070 us; speedup vs baseline: 3.2794x; 1.4295x over previous
//
#include <hip/hip_runtime.h>
#include <stdint.h>

// ---------------------------------------------------------------------------
// GPS (GINE + dense MHA + MLP, BatchNorm) forward, MI355X round-3.
// GEMMs on MFMA (m97 structure). Attention now MFMA-based: one wave per
// (graph, head), K/V^T fragments register-resident, P via swizzled LDS.
// ---------------------------------------------------------------------------

#define NN   65536
#define EE   524288
#define DD   256
#define LL   4
#define GG   512
#define NPGx 128
#define FFF  512

typedef __attribute__((ext_vector_type(8))) short short8;
typedef __attribute__((ext_vector_type(8))) __bf16 bf16x8;
typedef __attribute__((ext_vector_type(4))) float f32x4;

__device__ __forceinline__ float b2f(unsigned short u){
  union {unsigned int i; float f;} z; z.i = ((unsigned int)u) << 16; return z.f;
}
__device__ __forceinline__ unsigned short f2b(float f){
  union {float f; unsigned int i;} z; z.f = f;
  unsigned int r = z.i + 0x7fff + ((z.i >> 16) & 1u);
  return (unsigned short)(r >> 16);
}

__device__ __forceinline__ void gld16(void* lds, const void* g){
  __builtin_amdgcn_global_load_lds(
      (const __attribute__((address_space(1))) void*)g,
      (__attribute__((address_space(3))) void*)lds, 16, 0, 0);
}

// ---------------- preprocessing ----------------

__global__ __launch_bounds__(256) void combo_k(const float* __restrict__ be,
                                               unsigned short* __restrict__ tab){
  int c = blockIdx.x, d = threadIdx.x;
  int a0 = c & 7, a1 = (c >> 3) & 7, a2 = (c >> 6) & 7;
  tab[c*DD + d] = f2b(be[a0*DD + d] + be[(8 + a1)*DD + d] + be[(16 + a2)*DD + d]);
}

__global__ __launch_bounds__(256) void hist_k(const int* __restrict__ ei,
                                              int* __restrict__ cnt){
  for (int i = blockIdx.x*256 + threadIdx.x; i < EE; i += gridDim.x*256)
    atomicAdd(&cnt[ei[EE + i]], 1);
}

__global__ __launch_bounds__(1024) void scan_k(int* __restrict__ cnt,
                                               int* __restrict__ row_ptr){
  __shared__ int sd[1024];
  __shared__ int carry;
  int t = threadIdx.x;
  if (t == 0) carry = 0;
  __syncthreads();
  for (int base = 0; base < NN; base += 4096){
    int idx = base + t*4;
    int v0 = cnt[idx+0], v1 = cnt[idx+1], v2 = cnt[idx+2], v3 = cnt[idx+3];
    int s = v0 + v1 + v2 + v3;
    sd[t] = s; __syncthreads();
    for (int offd = 1; offd < 1024; offd <<= 1){
      int xv = (t >= offd) ? sd[t - offd] : 0;
      __syncthreads();
      sd[t] += xv;
      __syncthreads();
    }
    int excl = sd[t] - s + carry;
    row_ptr[idx+0] = excl;             cnt[idx+0] = excl;
    row_ptr[idx+1] = excl + v0;        cnt[idx+1] = excl + v0;
    row_ptr[idx+2] = excl + v0 + v1;   cnt[idx+2] = excl + v0 + v1;
    row_ptr[idx+3] = excl + v0+v1+v2;  cnt[idx+3] = excl + v0+v1+v2;
    __syncthreads();
    if (t == 0) carry += sd[1023];
    __syncthreads();
  }
  if (t == 0) row_ptr[NN] = carry;
}

__global__ __launch_bounds__(256) void fill_k(const int* __restrict__ ei,
                                              const int* __restrict__ ea,
                                              int* __restrict__ cursor,
                                              int* __restrict__ slot){
  for (int i = blockIdx.x*256 + threadIdx.x; i < EE; i += gridDim.x*256){
    int s  = ei[i];
    int dn = ei[EE + i];
    int a0 = ea[i*3+0], a1 = ea[i*3+1], a2 = ea[i*3+2];
    int cb = a0 | (a1 << 3) | (a2 << 6);
    int p = atomicAdd(&cursor[dn], 1);
    slot[p] = s | (cb << 16);
  }
}

// weight transpose + bf16
__global__ __launch_bounds__(256) void twt_k(const float* __restrict__ w1,
                                             const float* __restrict__ w2,
                                             const float* __restrict__ wqkv,
                                             const float* __restrict__ wo,
                                             const float* __restrict__ m1,
                                             const float* __restrict__ m2,
                                             unsigned short* __restrict__ wt){
  int l = blockIdx.x / 2304;
  int r = blockIdx.x % 2304;
  const float* src; unsigned short* dst; int K, Nsrc, n;
  unsigned short* wl = wt + (size_t)l*655360;
  if (r < 256)      { src = w1  +(size_t)l*65536;  dst = wl;          K=256; Nsrc=256; n=r; }
  else if (r < 512) { src = w2  +(size_t)l*65536;  dst = wl+65536;    K=256; Nsrc=256; n=r-256; }
  else if (r < 1280){ src = wqkv+(size_t)l*196608; dst = wl+131072;   K=256; Nsrc=768; n=r-512; }
  else if (r < 1536){ src = wo  +(size_t)l*65536;  dst = wl+327680;   K=256; Nsrc=256; n=r-1280; }
  else if (r < 2048){ src = m1  +(size_t)l*131072; dst = wl+393216;   K=256; Nsrc=512; n=r-1536; }
  else              { src = m2  +(size_t)l*131072; dst = wl+524288;   K=512; Nsrc=256; n=r-2048; }
  for (int k = threadIdx.x; k < K; k += 256)
    dst[(size_t)n*K + k] = f2b(src[(size_t)k*Nsrc + n]);
}

__global__ __launch_bounds__(256) void enc_k(const int* __restrict__ x,
                                             const float* __restrict__ pe,
                                             const float* __restrict__ atom_emb,
                                             const float* __restrict__ pe_w,
                                             const float* __restrict__ pe_b,
                                             unsigned short* __restrict__ hb){
  int n = blockIdx.x, d = threadIdx.x;
  __shared__ int xr[9];
  __shared__ float per[20];
  if (d < 9) xr[d] = x[n*9 + d];
  if (d >= 32 && d < 52) per[d-32] = pe[n*20 + (d-32)];
  __syncthreads();
  float acc = pe_b[d];
  #pragma unroll
  for (int i = 0; i < 9; i++) acc += atom_emb[(i*128 + xr[i])*DD + d];
  #pragma unroll
  for (int w = 0; w < 20; w++) acc += per[w] * pe_w[w*DD + d];
  hb[(size_t)n*DD + d] = f2b(acc);
}

// GINE gather: wave-per-node
__global__ __launch_bounds__(256) void gather_k(const unsigned short* __restrict__ hb,
                                                const int* __restrict__ row_ptr,
                                                const int* __restrict__ slot,
                                                const unsigned short* __restrict__ combo,
                                                unsigned short* __restrict__ t1){
  int w = threadIdx.x >> 6, lane = threadIdx.x & 63;
  int n = blockIdx.x*4 + w;
  int beg = row_ptr[n], end = row_ptr[n+1];
  int d0 = lane*4;
  float a0 = 0.f, a1 = 0.f, a2 = 0.f, a3 = 0.f;
  for (int e = beg; e < end; e++){
    int s = slot[e];
    int src = s & 0xFFFF;
    int cb  = ((unsigned)s) >> 16;
    ushort4 hv = *(const ushort4*)(hb + (size_t)src*DD + d0);
    ushort4 cv = *(const ushort4*)(combo + (size_t)cb*DD + d0);
    a0 += fmaxf(b2f(hv.x)+b2f(cv.x), 0.f);
    a1 += fmaxf(b2f(hv.y)+b2f(cv.y), 0.f);
    a2 += fmaxf(b2f(hv.z)+b2f(cv.z), 0.f);
    a3 += fmaxf(b2f(hv.w)+b2f(cv.w), 0.f);
  }
  ushort4 hn = *(const ushort4*)(hb + (size_t)n*DD + d0);
  ushort4 o;
  o.x = f2b(b2f(hn.x)+a0); o.y = f2b(b2f(hn.y)+a1);
  o.z = f2b(b2f(hn.z)+a2); o.w = f2b(b2f(hn.w)+a3);
  *(ushort4*)(t1 + (size_t)n*DD + d0) = o;
}

// ---------------- MFMA GEMM (m97 structure) ----------------
template<bool RELU, bool RES, bool STATS>
__global__ __launch_bounds__(256) void mgemm_k(
    const unsigned short* __restrict__ A,
    const unsigned short* __restrict__ Bt,
    const float* __restrict__ bias,
    const unsigned short* __restrict__ res,
    float* __restrict__ statsOut,
    unsigned short* __restrict__ C,
    int Nn, int K)
{
  __shared__ __align__(16) __bf16 As[4096];   // [128][32]
  __shared__ __align__(16) __bf16 Bs[4096];   // [128][32]
  __shared__ float cs[128];
  __shared__ float cq[128];
  int tid  = threadIdx.x;
  int wid  = tid >> 6, lane = tid & 63;
  int row0 = blockIdx.x * 128, col0 = blockIdx.y * 128;
  int wr = wid >> 1, wc = wid & 1;
  int lr = lane >> 2, lc = (lane & 3) * 8;
  int fr = lane & 15, fq = lane >> 4;

  if (STATS && tid < 128){ cs[tid] = 0.f; cq[tid] = 0.f; }

  f32x4 acc[4][4];
  #pragma unroll
  for (int i = 0; i < 4; i++)
    #pragma unroll
    for (int j = 0; j < 4; j++) acc[i][j] = f32x4{0.f, 0.f, 0.f, 0.f};

  const unsigned short* ga0 = A  + (size_t)(row0 + 16*wid     + lr)*K + lc;
  const unsigned short* ga1 = A  + (size_t)(row0 + 16*(wid+4) + lr)*K + lc;
  const unsigned short* gb0 = Bt + (size_t)(col0 + 16*wid     + lr)*K + lc;
  const unsigned short* gb1 = Bt + (size_t)(col0 + 16*(wid+4) + lr)*K + lc;

  for (int kt = 0; kt < K; kt += 32){
    __syncthreads();
    gld16(&As[wid*512],     ga0 + kt);
    gld16(&As[(wid+4)*512], ga1 + kt);
    gld16(&Bs[wid*512],     gb0 + kt);
    gld16(&Bs[(wid+4)*512], gb1 + kt);
    __syncthreads();
    bf16x8 a[4], b[4];
    #pragma unroll
    for (int i = 0; i < 4; i++)
      a[i] = *(const bf16x8*)&As[(wr*64 + 16*i + fr)*32 + fq*8];
    #pragma unroll
    for (int j = 0; j < 4; j++)
      b[j] = *(const bf16x8*)&Bs[(wc*64 + 16*j + fr)*32 + fq*8];
    #pragma unroll
    for (int i = 0; i < 4; i++)
      #pragma unroll
      for (int j = 0; j < 4; j++)
        acc[i][j] = __builtin_amdgcn_mfma_f32_16x16x32_bf16(a[i], b[j], acc[i][j], 0, 0, 0);
  }

  float bj[4];
  #pragma unroll
  for (int j = 0; j < 4; j++) bj[j] = bias[col0 + wc*64 + 16*j + fr];

  #pragma unroll
  for (int i = 0; i < 4; i++){
    #pragma unroll
    for (int j = 0; j < 4; j++){
      int col = col0 + wc*64 + 16*j + fr;
      #pragma unroll
      for (int r = 0; r < 4; r++){
        int row = row0 + wr*64 + 16*i + fq*4 + r;
        float y = acc[i][j][r] + bj[j];
        if constexpr (RELU) y = fmaxf(y, 0.f);
        if constexpr (RES)  y += b2f(res[(size_t)row*Nn + col]);
        acc[i][j][r] = y;
        C[(size_t)row*Nn + col] = f2b(y);
      }
    }
  }

  if constexpr (STATS){
    #pragma unroll
    for (int j = 0; j < 4; j++){
      float ps = 0.f, pq = 0.f;
      #pragma unroll
      for (int i = 0; i < 4; i++)
        #pragma unroll
        for (int r = 0; r < 4; r++){ float v = acc[i][j][r]; ps += v; pq += v*v; }
      ps += __shfl_xor(ps, 16, 64); pq += __shfl_xor(pq, 16, 64);
      ps += __shfl_xor(ps, 32, 64); pq += __shfl_xor(pq, 32, 64);
      if (lane < 16){
        atomicAdd(&cs[wc*64 + 16*j + fr], ps);
        atomicAdd(&cq[wc*64 + 16*j + fr], pq);
      }
    }
    __syncthreads();
    if (tid < 128){
      atomicAdd(&statsOut[col0 + tid],       cs[tid]);
      atomicAdd(&statsOut[256 + col0 + tid], cq[tid]);
    }
  }
}

// in-place BN (+optional relu)
template<bool RELU>
__global__ __launch_bounds__(256) void bnap_k(unsigned short* __restrict__ t,
                                              const float* __restrict__ st,
                                              const float* __restrict__ g,
                                              const float* __restrict__ b){
  __shared__ float sc[256], sh[256];
  int tid = threadIdx.x;
  {
    float mu  = st[tid] * (1.f/NN);
    float var = st[256+tid] * (1.f/NN) - mu*mu;
    float s   = rsqrtf(var + 1e-5f) * g[tid];
    sc[tid] = s; sh[tid] = b[tid] - mu*s;
  }
  __syncthreads();
  size_t base = ((size_t)blockIdx.x*256 + tid)*8;
  int c0 = (int)(base & 255);
  short8 v = *(const short8*)(t + base);
  short8 o;
  #pragma unroll
  for (int u = 0; u < 8; u++){
    float f = b2f((unsigned short)v[u])*sc[c0+u] + sh[c0+u];
    if constexpr (RELU) f = fmaxf(f, 0.f);
    o[u] = (short)f2b(f);
  }
  *(short8*)(t + base) = o;
}

// X = bn(t1;S1,n1) + bn(t4;S2,n2)
__global__ __launch_bounds__(256) void combine_k(
    const unsigned short* __restrict__ t1, const unsigned short* __restrict__ t4,
    const float* __restrict__ S1, const float* __restrict__ g1, const float* __restrict__ b1,
    const float* __restrict__ S2, const float* __restrict__ g2, const float* __restrict__ b2,
    unsigned short* __restrict__ X)
{
  __shared__ float sc1[256], sh1[256], sc2[256], sh2[256];
  int tid = threadIdx.x;
  {
    float mu1 = S1[tid]*(1.f/NN), va1 = S1[256+tid]*(1.f/NN) - mu1*mu1;
    float s1 = rsqrtf(va1+1e-5f)*g1[tid]; sc1[tid]=s1; sh1[tid]=b1[tid]-mu1*s1;
    float mu2 = S2[tid]*(1.f/NN), va2 = S2[256+tid]*(1.f/NN) - mu2*mu2;
    float s2 = rsqrtf(va2+1e-5f)*g2[tid]; sc2[tid]=s2; sh2[tid]=b2[tid]-mu2*s2;
  }
  __syncthreads();
  size_t base = ((size_t)blockIdx.x*256 + tid)*8;
  int c0 = (int)(base & 255);
  short8 v1 = *(const short8*)(t1 + base);
  short8 v4 = *(const short8*)(t4 + base);
  short8 o;
  #pragma unroll
  for (int u = 0; u < 8; u++){
    float f = b2f((unsigned short)v1[u])*sc1[c0+u] + sh1[c0+u]
            + b2f((unsigned short)v4[u])*sc2[c0+u] + sh2[c0+u];
    o[u] = (short)f2b(f);
  }
  *(short8*)(X + base) = o;
}

// ---------------- MFMA attention: one wave per (graph, head) ----------------
// S = Q@K^T via mfma (DH=32 -> K=32, single step). K-frags and V^T-frags are
// strip-invariant -> register-resident. P acc->A-frag relayout via swizzled LDS.
__global__ __launch_bounds__(64) void attn_k(const unsigned short* __restrict__ qkv,
                                             unsigned short* __restrict__ o_out){
  int g  = blockIdx.x >> 3;
  int hh = blockIdx.x & 7;
  int lane = threadIdx.x;
  int fr = lane & 15, fq = lane >> 4;
  __shared__ __align__(16) unsigned short Vt[32*136];  // [d][n], stride 136 (bank-balanced)
  __shared__ __align__(16) unsigned short P[16*128];   // swizzled strip

  const unsigned short* qb = qkv + (size_t)g*128*768 + hh*32;
  const unsigned short* kb = qb + 256;
  const unsigned short* vb = qb + 512;

  // stage V^T (each lane: rows n=lane, n+64)
  #pragma unroll
  for (int h2 = 0; h2 < 2; h2++){
    int n = lane + 64*h2;
    const short8* vr = (const short8*)(vb + (size_t)n*768);
    #pragma unroll
    for (int c = 0; c < 4; c++){
      short8 v = vr[c];
      #pragma unroll
      for (int u = 0; u < 8; u++)
        Vt[(c*8+u)*136 + n] = (unsigned short)v[u];
    }
  }
  // K fragments (register-resident): bk[j] = K[16j+fr][fq*8 .. +8]
  bf16x8 bk[8];
  #pragma unroll
  for (int j = 0; j < 8; j++)
    bk[j] = *(const bf16x8*)(kb + (size_t)(16*j + fr)*768 + fq*8);
  __syncthreads();
  // V^T fragments (register-resident): bv[kk][j2] = Vt[16j2+fr][kk*32+fq*8 ..]
  bf16x8 bv[4][2];
  #pragma unroll
  for (int kk = 0; kk < 4; kk++)
    #pragma unroll
    for (int j2 = 0; j2 < 2; j2++)
      bv[kk][j2] = *(const bf16x8*)&Vt[(16*j2 + fr)*136 + kk*32 + fq*8];

  const float SCALE = 0.17677669529663687f;   // 1/sqrt(32)
  for (int m0 = 0; m0 < 128; m0 += 16){
    bf16x8 aq = *(const bf16x8*)(qb + (size_t)(m0 + fr)*768 + fq*8);
    f32x4 s[8];
    #pragma unroll
    for (int j = 0; j < 8; j++)
      s[j] = __builtin_amdgcn_mfma_f32_16x16x32_bf16(aq, bk[j], f32x4{0.f,0.f,0.f,0.f}, 0, 0, 0);
    // softmax over each of this lane's 4 rows (row = fq*4+r, cols fr+16j)
    float linv[4];
    #pragma unroll
    for (int r = 0; r < 4; r++){
      float mx = s[0][r];
      #pragma unroll
      for (int j = 1; j < 8; j++) mx = fmaxf(mx, s[j][r]);
      mx = fmaxf(mx, __shfl_xor(mx, 1, 64));
      mx = fmaxf(mx, __shfl_xor(mx, 2, 64));
      mx = fmaxf(mx, __shfl_xor(mx, 4, 64));
      mx = fmaxf(mx, __shfl_xor(mx, 8, 64));
      float sum = 0.f;
      #pragma unroll
      for (int j = 0; j < 8; j++){
        float p = __expf((s[j][r] - mx) * SCALE);
        unsigned short pb = f2b(p);
        s[j][r] = b2f(pb);              // use rounded value for both PV and sum
        sum += s[j][r];
      }
      sum += __shfl_xor(sum, 1, 64);
      sum += __shfl_xor(sum, 2, 64);
      sum += __shfl_xor(sum, 4, 64);
      sum += __shfl_xor(sum, 8, 64);
      linv[r] = 1.f / sum;
    }
    // write P strip to LDS (swizzle col ^= (row&7)<<3, 16B-granular)
    #pragma unroll
    for (int j = 0; j < 8; j++)
      #pragma unroll
      for (int r = 0; r < 4; r++){
        int row = fq*4 + r;
        int col = (16*j + fr) ^ ((row & 7) << 3);
        P[row*128 + col] = f2b(s[j][r]);
      }
    __syncthreads();
    f32x4 o0 = {0.f,0.f,0.f,0.f}, o1 = {0.f,0.f,0.f,0.f};
    #pragma unroll
    for (int kk = 0; kk < 4; kk++){
      bf16x8 pa = *(const bf16x8*)&P[fr*128 + ((kk*32 + fq*8) ^ ((fr & 7) << 3))];
      o0 = __builtin_amdgcn_mfma_f32_16x16x32_bf16(pa, bv[kk][0], o0, 0, 0, 0);
      o1 = __builtin_amdgcn_mfma_f32_16x16x32_bf16(pa, bv[kk][1], o1, 0, 0, 0);
    }
    #pragma unroll
    for (int r = 0; r < 4; r++){
      int row = g*128 + m0 + fq*4 + r;
      unsigned short* dst = o_out + (size_t)row*DD + hh*32;
      dst[fr]      = f2b(o0[r]*linv[r]);
      dst[16 + fr] = f2b(o1[r]*linv[r]);
    }
    __syncthreads();   // P reused next strip
  }
}

// global_add_pool
__global__ __launch_bounds__(256) void pool_k(const unsigned short* __restrict__ hb,
                                              float* __restrict__ out){
  int g = blockIdx.x, d = threadIdx.x;
  float acc = 0.f;
  for (int r = 0; r < NPGx; r++) acc += b2f(hb[(size_t)(g*NPGx + r)*DD + d]);
  out[g*DD + d] = acc;
}

// ---------------------------------------------------------------------------

extern "C" void kernel_launch(void* const* d_in, const int* in_sizes, int n_in,
                              void* d_out, int out_size, void* d_ws, size_t ws_size,
                              hipStream_t stream)
{
  const int*   x         = (const int*)  d_in[0];
  const int*   ei        = (const int*)  d_in[1];
  const int*   ea        = (const int*)  d_in[2];
  const float* pe        = (const float*)d_in[4];
  const float* atom_emb  = (const float*)d_in[5];
  const float* bond_emb  = (const float*)d_in[6];
  const float* pe_w      = (const float*)d_in[7];
  const float* pe_b      = (const float*)d_in[8];
  const float* gine_w1   = (const float*)d_in[9];
  const float* gine_b1   = (const float*)d_in[10];
  const float* gine_g1   = (const float*)d_in[11];
  const float* gine_be1  = (const float*)d_in[12];
  const float* gine_w2   = (const float*)d_in[13];
  const float* gine_b2   = (const float*)d_in[14];
  const float* attn_wqkv = (const float*)d_in[15];
  const float* attn_bqkv = (const float*)d_in[16];
  const float* attn_wo   = (const float*)d_in[17];
  const float* attn_bo   = (const float*)d_in[18];
  const float* n1_g      = (const float*)d_in[19];
  const float* n1_b      = (const float*)d_in[20];
  const float* n2_g      = (const float*)d_in[21];
  const float* n2_b      = (const float*)d_in[22];
  const float* n3_g      = (const float*)d_in[23];
  const float* n3_b      = (const float*)d_in[24];
  const float* mlp_w1    = (const float*)d_in[25];
  const float* mlp_b1    = (const float*)d_in[26];
  const float* mlp_w2    = (const float*)d_in[27];
  const float* mlp_b2    = (const float*)d_in[28];
  float* out = (float*)d_out;

  char* wsp = (char*)d_ws;
  size_t off = 0;
  auto alloc = [&](size_t bytes)->void*{
    void* p = wsp + off; off += (bytes + 255) & ~(size_t)255; return p;
  };
  unsigned short* hb  = (unsigned short*)alloc((size_t)NN*DD*2);
  unsigned short* t1  = (unsigned short*)alloc((size_t)NN*DD*2);
  unsigned short* t2  = (unsigned short*)alloc((size_t)NN*DD*2);
  unsigned short* t4  = (unsigned short*)alloc((size_t)NN*DD*2);
  unsigned short* big = (unsigned short*)alloc((size_t)NN*768*2);
  unsigned short* wt  = (unsigned short*)alloc((size_t)LL*655360*2);
  unsigned short* combo = (unsigned short*)alloc((size_t)512*DD*2);
  int*   row_ptr = (int*)  alloc((size_t)(NN+1)*4);
  int*   cursor  = (int*)  alloc((size_t)NN*4);
  int*   slot    = (int*)  alloc((size_t)EE*4);
  float* stats   = (float*)alloc((size_t)LL*4*2*DD*4);
  if (off > ws_size) return;

  hipMemsetAsync(stats,  0, (size_t)LL*4*2*DD*4, stream);
  hipMemsetAsync(cursor, 0, (size_t)NN*4, stream);
  combo_k<<<512, 256, 0, stream>>>(bond_emb, combo);
  twt_k  <<<LL*2304, 256, 0, stream>>>(gine_w1, gine_w2, attn_wqkv, attn_wo,
                                       mlp_w1, mlp_w2, wt);
  hist_k <<<512, 256, 0, stream>>>(ei, cursor);
  scan_k <<<1, 1024, 0, stream>>>(cursor, row_ptr);
  fill_k <<<512, 256, 0, stream>>>(ei, ea, cursor, slot);
  enc_k  <<<NN, 256, 0, stream>>>(x, pe, atom_emb, pe_w, pe_b, hb);

  for (int l = 0; l < LL; l++){
    unsigned short* wl = wt + (size_t)l*655360;
    const float* b1   = gine_b1   + l*DD;
    const float* b2   = gine_b2   + l*DD;
    const float* bqkv = attn_bqkv + l*768;
    const float* bo   = attn_bo   + l*DD;
    const float* mb1  = mlp_b1    + l*FFF;
    const float* mb2  = mlp_b2    + l*DD;
    float* S0 = stats + (l*4+0)*2*DD;
    float* S1 = stats + (l*4+1)*2*DD;
    float* S2 = stats + (l*4+2)*2*DD;
    float* S3 = stats + (l*4+3)*2*DD;

    gather_k<<<NN/4, 256, 0, stream>>>(hb, row_ptr, slot, combo, t1);
    mgemm_k<false,false,true><<<dim3(NN/128, 2), 256, 0, stream>>>(
        t1, wl + 0, b1, nullptr, S0, t2, 256, 256);
    bnap_k<true><<<NN*DD/2048, 256, 0, stream>>>(t2, S0, gine_g1 + l*DD, gine_be1 + l*DD);
    mgemm_k<true,true,true><<<dim3(NN/128, 2), 256, 0, stream>>>(
        t2, wl + 65536, b2, hb, S1, t1, 256, 256);
    mgemm_k<false,false,false><<<dim3(NN/128, 6), 256, 0, stream>>>(
        hb, wl + 131072, bqkv, nullptr, nullptr, big, 768, 256);
    attn_k<<<GG*8, 64, 0, stream>>>(big, t2);
    mgemm_k<false,true,true><<<dim3(NN/128, 2), 256, 0, stream>>>(
        t2, wl + 327680, bo, hb, S2, t4, 256, 256);
    combine_k<<<NN*DD/2048, 256, 0, stream>>>(
        t1, t4, S1, n1_g + l*DD, n1_b + l*DD, S2, n2_g + l*DD, n2_b + l*DD, t2);
    mgemm_k<true,false,false><<<dim3(NN/128, 4), 256, 0, stream>>>(
        t2, wl + 393216, mb1, nullptr, nullptr, big, 512, 256);
    mgemm_k<false,false,true><<<dim3(NN/128, 2), 256, 0, stream>>>(
        big, wl + 524288, mb2, nullptr, S3, hb, 256, 512);
    bnap_k<false><<<NN*DD/2048, 256, 0, stream>>>(hb, S3, n3_g + l*DD, n3_b + l*DD);
  }
  pool_k<<<GG, 256, 0, stream>>>(hb, out);
}

// Round 4
// 1655.955 us; speedup vs baseline: 4.2144x; 1.2851x over previous
//
#include <hip/hip_runtime.h>
#include <stdint.h>

// ---------------------------------------------------------------------------
// GPS (GINE + dense MHA + MLP, BatchNorm) forward, MI355X round-4.
// GEMMs: 256x256 tile, 8 waves (2x4), wave-tile 128x64, BK=64, double-buffered
// LDS with early-STAGE 2-phase schedule + XOR chunk swizzle (both-sides).
// BN folded into consumer GEMM prologues (reg-staged A variants).
// ---------------------------------------------------------------------------

#define NN   65536
#define EE   524288
#define DD   256
#define LL   4
#define GG   512
#define NPGx 128
#define FFF  512

typedef __attribute__((ext_vector_type(8))) short short8;
typedef __attribute__((ext_vector_type(8))) __bf16 bf16x8;
typedef __attribute__((ext_vector_type(4))) float f32x4;

__device__ __forceinline__ float b2f(unsigned short u){
  union {unsigned int i; float f;} z; z.i = ((unsigned int)u) << 16; return z.f;
}
__device__ __forceinline__ unsigned short f2b(float f){
  union {float f; unsigned int i;} z; z.f = f;
  unsigned int r = z.i + 0x7fff + ((z.i >> 16) & 1u);
  return (unsigned short)(r >> 16);
}

__device__ __forceinline__ void gld16(void* lds, const void* g){
  __builtin_amdgcn_global_load_lds(
      (const __attribute__((address_space(1))) void*)g,
      (__attribute__((address_space(3))) void*)lds, 16, 0, 0);
}

// ---------------- preprocessing ----------------

__global__ __launch_bounds__(256) void combo_k(const float* __restrict__ be,
                                               unsigned short* __restrict__ tab){
  int c = blockIdx.x, d = threadIdx.x;
  int a0 = c & 7, a1 = (c >> 3) & 7, a2 = (c >> 6) & 7;
  tab[c*DD + d] = f2b(be[a0*DD + d] + be[(8 + a1)*DD + d] + be[(16 + a2)*DD + d]);
}

__global__ __launch_bounds__(256) void hist_k(const int* __restrict__ ei,
                                              int* __restrict__ cnt){
  for (int i = blockIdx.x*256 + threadIdx.x; i < EE; i += gridDim.x*256)
    atomicAdd(&cnt[ei[EE + i]], 1);
}

__global__ __launch_bounds__(1024) void scan_k(int* __restrict__ cnt,
                                               int* __restrict__ row_ptr){
  __shared__ int sd[1024];
  __shared__ int carry;
  int t = threadIdx.x;
  if (t == 0) carry = 0;
  __syncthreads();
  for (int base = 0; base < NN; base += 4096){
    int idx = base + t*4;
    int v0 = cnt[idx+0], v1 = cnt[idx+1], v2 = cnt[idx+2], v3 = cnt[idx+3];
    int s = v0 + v1 + v2 + v3;
    sd[t] = s; __syncthreads();
    for (int offd = 1; offd < 1024; offd <<= 1){
      int xv = (t >= offd) ? sd[t - offd] : 0;
      __syncthreads();
      sd[t] += xv;
      __syncthreads();
    }
    int excl = sd[t] - s + carry;
    row_ptr[idx+0] = excl;             cnt[idx+0] = excl;
    row_ptr[idx+1] = excl + v0;        cnt[idx+1] = excl + v0;
    row_ptr[idx+2] = excl + v0 + v1;   cnt[idx+2] = excl + v0 + v1;
    row_ptr[idx+3] = excl + v0+v1+v2;  cnt[idx+3] = excl + v0+v1+v2;
    __syncthreads();
    if (t == 0) carry += sd[1023];
    __syncthreads();
  }
  if (t == 0) row_ptr[NN] = carry;
}

__global__ __launch_bounds__(256) void fill_k(const int* __restrict__ ei,
                                              const int* __restrict__ ea,
                                              int* __restrict__ cursor,
                                              int* __restrict__ slot){
  for (int i = blockIdx.x*256 + threadIdx.x; i < EE; i += gridDim.x*256){
    int s  = ei[i];
    int dn = ei[EE + i];
    int a0 = ea[i*3+0], a1 = ea[i*3+1], a2 = ea[i*3+2];
    int cb = a0 | (a1 << 3) | (a2 << 6);
    int p = atomicAdd(&cursor[dn], 1);
    slot[p] = s | (cb << 16);
  }
}

// weight transpose + bf16
__global__ __launch_bounds__(256) void twt_k(const float* __restrict__ w1,
                                             const float* __restrict__ w2,
                                             const float* __restrict__ wqkv,
                                             const float* __restrict__ wo,
                                             const float* __restrict__ m1,
                                             const float* __restrict__ m2,
                                             unsigned short* __restrict__ wt){
  int l = blockIdx.x / 2304;
  int r = blockIdx.x % 2304;
  const float* src; unsigned short* dst; int K, Nsrc, n;
  unsigned short* wl = wt + (size_t)l*655360;
  if (r < 256)      { src = w1  +(size_t)l*65536;  dst = wl;          K=256; Nsrc=256; n=r; }
  else if (r < 512) { src = w2  +(size_t)l*65536;  dst = wl+65536;    K=256; Nsrc=256; n=r-256; }
  else if (r < 1280){ src = wqkv+(size_t)l*196608; dst = wl+131072;   K=256; Nsrc=768; n=r-512; }
  else if (r < 1536){ src = wo  +(size_t)l*65536;  dst = wl+327680;   K=256; Nsrc=256; n=r-1280; }
  else if (r < 2048){ src = m1  +(size_t)l*131072; dst = wl+393216;   K=256; Nsrc=512; n=r-1536; }
  else              { src = m2  +(size_t)l*131072; dst = wl+524288;   K=512; Nsrc=256; n=r-2048; }
  for (int k = threadIdx.x; k < K; k += 256)
    dst[(size_t)n*K + k] = f2b(src[(size_t)k*Nsrc + n]);
}

// AtomEncoder + PE: wave per node, f32x4 vector loads
__global__ __launch_bounds__(256) void enc_k(const int* __restrict__ x,
                                             const float* __restrict__ pe,
                                             const float* __restrict__ atom_emb,
                                             const float* __restrict__ pe_w,
                                             const float* __restrict__ pe_b,
                                             unsigned short* __restrict__ hb){
  int w = threadIdx.x >> 6, lane = threadIdx.x & 63;
  int n = blockIdx.x*4 + w;
  int d0 = lane*4;
  f32x4 acc = *(const f32x4*)(pe_b + d0);
  #pragma unroll
  for (int i = 0; i < 9; i++){
    int xi = x[n*9 + i];
    f32x4 v = *(const f32x4*)(atom_emb + (size_t)(i*128 + xi)*DD + d0);
    acc += v;
  }
  #pragma unroll
  for (int t = 0; t < 20; t++){
    float p = pe[n*20 + t];
    f32x4 v = *(const f32x4*)(pe_w + (size_t)t*DD + d0);
    acc += p * v;
  }
  ushort4 o;
  o.x = f2b(acc[0]); o.y = f2b(acc[1]); o.z = f2b(acc[2]); o.w = f2b(acc[3]);
  *(ushort4*)(hb + (size_t)n*DD + d0) = o;
}

// GINE gather: wave per node, 2 edges/iteration (32 lanes x 16B per edge row)
__global__ __launch_bounds__(256) void gather_k(const unsigned short* __restrict__ hb,
                                                const int* __restrict__ row_ptr,
                                                const int* __restrict__ slot,
                                                const unsigned short* __restrict__ combo,
                                                unsigned short* __restrict__ t1){
  int w = threadIdx.x >> 6, lane = threadIdx.x & 63;
  int n = blockIdx.x*4 + w;
  int half = lane >> 5, l32 = lane & 31;
  int d0 = l32*8;
  int beg = row_ptr[n], end = row_ptr[n+1];
  float acc[8];
  #pragma unroll
  for (int u = 0; u < 8; u++) acc[u] = 0.f;
  for (int e = beg + half; e < end; e += 2){
    int s = slot[e];
    int src = s & 0xFFFF;
    int cb  = ((unsigned)s) >> 16;
    short8 hv = *(const short8*)(hb + (size_t)src*DD + d0);
    short8 cv = *(const short8*)(combo + (size_t)cb*DD + d0);
    #pragma unroll
    for (int u = 0; u < 8; u++)
      acc[u] += fmaxf(b2f((unsigned short)hv[u]) + b2f((unsigned short)cv[u]), 0.f);
  }
  #pragma unroll
  for (int u = 0; u < 8; u++) acc[u] += __shfl_xor(acc[u], 32, 64);
  if (half == 0){
    short8 hn = *(const short8*)(hb + (size_t)n*DD + d0);
    short8 o;
    #pragma unroll
    for (int u = 0; u < 8; u++) o[u] = (short)f2b(b2f((unsigned short)hn[u]) + acc[u]);
    *(short8*)(t1 + (size_t)n*DD + d0) = o;
  }
}

// ---------------- MFMA GEMM: 256x256 tile, 8 waves, BK=64, dbuf 2-phase -----
// PRO 0: A staged via global_load_lds (pre-swizzled source)
// PRO 1: A = relu(bn(A; st1,g1,b1))  (reg-staged, swizzled ds_write)
// PRO 2: A = bn(A;st1,g1,b1) + bn(A2;st2,g2,b2)
template<int PRO, bool RELU, bool RES, bool STATS>
__global__ __launch_bounds__(512, 2) void mgemm_k(
    const unsigned short* __restrict__ A,
    const unsigned short* __restrict__ A2,
    const unsigned short* __restrict__ Bt,
    const float* __restrict__ bias,
    const unsigned short* __restrict__ res,
    const float* __restrict__ stIn1, const float* __restrict__ gg1, const float* __restrict__ bb1,
    const float* __restrict__ stIn2, const float* __restrict__ gg2, const float* __restrict__ bb2,
    float* __restrict__ statsOut,
    unsigned short* __restrict__ C,
    int Nn, int K)
{
  __shared__ __align__(16) __bf16 SA[2][256*64];
  __shared__ __align__(16) __bf16 SB[2][256*64];
  __shared__ float cs[256], cq[256];
  __shared__ __align__(16) float scF1[256], shF1[256], scF2[256], shF2[256];

  const int tid  = threadIdx.x;
  const int wid  = tid >> 6, lane = tid & 63;
  const int row0 = blockIdx.x * 256, col0 = blockIdx.y * 256;
  const int wrr = wid >> 2, wcc = wid & 3;         // wave tile: 128 rows x 64 cols
  const int fr = lane & 15, fq = lane >> 4;
  const int lr8 = lane >> 3, lc8 = lane & 7;       // staging lane mapping
  const int sc8 = lc8 ^ lr8;                       // pre-swizzled source chunk
  const int nt = K >> 6;

  if (STATS && tid < 256){ cs[tid] = 0.f; cq[tid] = 0.f; }
  if (PRO >= 1 && tid < 256){
    float mu = stIn1[tid]*(1.f/NN);
    float var = stIn1[256+tid]*(1.f/NN) - mu*mu;
    float s = rsqrtf(var + 1e-5f) * gg1[tid];
    scF1[tid] = s; shF1[tid] = bb1[tid] - mu*s;
    if (PRO == 2){
      float mu2 = stIn2[tid]*(1.f/NN);
      float va2 = stIn2[256+tid]*(1.f/NN) - mu2*mu2;
      float s2 = rsqrtf(va2 + 1e-5f) * gg2[tid];
      scF2[tid] = s2; shF2[tid] = bb2[tid] - mu2*s2;
    }
  }

  f32x4 acc[8][4];
  #pragma unroll
  for (int i = 0; i < 8; i++)
    #pragma unroll
    for (int j = 0; j < 4; j++) acc[i][j] = f32x4{0.f,0.f,0.f,0.f};

  // staging lambdas -------------------------------------------------------
  auto stageA = [&](int buf, int kt){
    #pragma unroll
    for (int q = 0; q < 4; q++)
      gld16(&SA[buf][(wid*32 + q*8)*64],
            A + (size_t)(row0 + wid*32 + q*8 + lr8)*K + kt + sc8*8);
  };
  auto stageB = [&](int buf, int kt){
    #pragma unroll
    for (int q = 0; q < 4; q++)
      gld16(&SB[buf][(wid*32 + q*8)*64],
            Bt + (size_t)(col0 + wid*32 + q*8 + lr8)*K + kt + sc8*8);
  };

  short8 g1v[4], g4v[4];
  auto loadA = [&](int kt){
    #pragma unroll
    for (int q = 0; q < 4; q++){
      size_t rw = (size_t)(row0 + wid*32 + q*8 + lr8);
      g1v[q] = *(const short8*)(A + rw*K + kt + lc8*8);
      if (PRO == 2) g4v[q] = *(const short8*)(A2 + rw*K + kt + lc8*8);
    }
  };
  auto dswA = [&](int buf, int kt){
    const f32x4* sp1 = (const f32x4*)&scF1[kt + lc8*8];
    const f32x4* hp1 = (const f32x4*)&shF1[kt + lc8*8];
    f32x4 s1a = sp1[0], s1b = sp1[1], h1a = hp1[0], h1b = hp1[1];
    f32x4 s2a, s2b, h2a, h2b;
    if (PRO == 2){
      const f32x4* sp2 = (const f32x4*)&scF2[kt + lc8*8];
      const f32x4* hp2 = (const f32x4*)&shF2[kt + lc8*8];
      s2a = sp2[0]; s2b = sp2[1]; h2a = hp2[0]; h2b = hp2[1];
    }
    #pragma unroll
    for (int q = 0; q < 4; q++){
      short8 o;
      #pragma unroll
      for (int u = 0; u < 8; u++){
        float sc = (u < 4) ? s1a[u&3] : s1b[u&3];
        float sh = (u < 4) ? h1a[u&3] : h1b[u&3];
        float v = b2f((unsigned short)g1v[q][u]) * sc + sh;
        if (PRO == 1) v = fmaxf(v, 0.f);
        if (PRO == 2){
          float sc2 = (u < 4) ? s2a[u&3] : s2b[u&3];
          float sh2 = (u < 4) ? h2a[u&3] : h2b[u&3];
          v += b2f((unsigned short)g4v[q][u]) * sc2 + sh2;
        }
        o[u] = (short)f2b(v);
      }
      *(short8*)&SA[buf][(wid*32 + q*8 + lr8)*64 + (lc8 ^ lr8)*8] = o;
    }
  };

  // prologue ---------------------------------------------------------------
  if (PRO == 0){
    stageA(0, 0); stageB(0, 0);
  } else {
    loadA(0); stageB(0, 0);
    __syncthreads();                 // scF/shF visible before first dswA
  }

  // K loop: one barrier per K-step, stage(t+1) overlaps compute(t) ---------
  int cur = 0;
  for (int t = 0; t < nt; t++){
    if (PRO == 0){
      __syncthreads();                               // buf[cur] staged
      if (t+1 < nt){ stageA(cur^1, (t+1)*64); stageB(cur^1, (t+1)*64); }
    } else {
      dswA(cur, t*64);
      __syncthreads();                               // A writes + B[cur] staged
      if (t+1 < nt){ loadA((t+1)*64); stageB(cur^1, (t+1)*64); }
    }
    #pragma unroll
    for (int ks = 0; ks < 2; ks++){
      int kc = ((ks*4 + fq) ^ (fr & 7)) * 8;
      bf16x8 a[8], b[4];
      #pragma unroll
      for (int i = 0; i < 8; i++)
        a[i] = *(const bf16x8*)&SA[cur][(wrr*128 + 16*i + fr)*64 + kc];
      #pragma unroll
      for (int j = 0; j < 4; j++)
        b[j] = *(const bf16x8*)&SB[cur][(wcc*64 + 16*j + fr)*64 + kc];
      #pragma unroll
      for (int i = 0; i < 8; i++)
        #pragma unroll
        for (int j = 0; j < 4; j++)
          acc[i][j] = __builtin_amdgcn_mfma_f32_16x16x32_bf16(a[i], b[j], acc[i][j], 0, 0, 0);
    }
    cur ^= 1;
  }

  // epilogue ---------------------------------------------------------------
  float bj[4];
  #pragma unroll
  for (int j = 0; j < 4; j++) bj[j] = bias[col0 + wcc*64 + 16*j + fr];

  #pragma unroll
  for (int i = 0; i < 8; i++){
    #pragma unroll
    for (int j = 0; j < 4; j++){
      int col = col0 + wcc*64 + 16*j + fr;
      #pragma unroll
      for (int r = 0; r < 4; r++){
        int row = row0 + wrr*128 + 16*i + fq*4 + r;
        float y = acc[i][j][r] + bj[j];
        if constexpr (RELU) y = fmaxf(y, 0.f);
        if constexpr (RES)  y += b2f(res[(size_t)row*256 + col]);
        acc[i][j][r] = y;
        C[(size_t)row*Nn + col] = f2b(y);
      }
    }
  }

  if constexpr (STATS){
    #pragma unroll
    for (int j = 0; j < 4; j++){
      float ps = 0.f, pq = 0.f;
      #pragma unroll
      for (int i = 0; i < 8; i++)
        #pragma unroll
        for (int r = 0; r < 4; r++){ float v = acc[i][j][r]; ps += v; pq += v*v; }
      ps += __shfl_xor(ps, 16, 64); pq += __shfl_xor(pq, 16, 64);
      ps += __shfl_xor(ps, 32, 64); pq += __shfl_xor(pq, 32, 64);
      if (lane < 16){
        atomicAdd(&cs[wcc*64 + 16*j + fr], ps);
        atomicAdd(&cq[wcc*64 + 16*j + fr], pq);
      }
    }
    __syncthreads();
    if (tid < 256){
      atomicAdd(&statsOut[tid],       cs[tid]);
      atomicAdd(&statsOut[256 + tid], cq[tid]);
    }
  }
}

// in-place BN apply (post-mlp2)
__global__ __launch_bounds__(256) void bnf_k(unsigned short* __restrict__ t,
                                             const float* __restrict__ st,
                                             const float* __restrict__ g,
                                             const float* __restrict__ b){
  __shared__ float sc[256], sh[256];
  int tid = threadIdx.x;
  {
    float mu  = st[tid] * (1.f/NN);
    float var = st[256+tid] * (1.f/NN) - mu*mu;
    float s   = rsqrtf(var + 1e-5f) * g[tid];
    sc[tid] = s; sh[tid] = b[tid] - mu*s;
  }
  __syncthreads();
  size_t base = ((size_t)blockIdx.x*256 + tid)*8;
  int c0 = (int)(base & 255);
  short8 v = *(const short8*)(t + base);
  short8 o;
  #pragma unroll
  for (int u = 0; u < 8; u++){
    float f = b2f((unsigned short)v[u])*sc[c0+u] + sh[c0+u];
    o[u] = (short)f2b(f);
  }
  *(short8*)(t + base) = o;
}

// ---------------- MFMA attention (round-3, verified) ----------------
__global__ __launch_bounds__(64) void attn_k(const unsigned short* __restrict__ qkv,
                                             unsigned short* __restrict__ o_out){
  int g  = blockIdx.x >> 3;
  int hh = blockIdx.x & 7;
  int lane = threadIdx.x;
  int fr = lane & 15, fq = lane >> 4;
  __shared__ __align__(16) unsigned short Vt[32*136];
  __shared__ __align__(16) unsigned short P[16*128];

  const unsigned short* qb = qkv + (size_t)g*128*768 + hh*32;
  const unsigned short* kb = qb + 256;
  const unsigned short* vb = qb + 512;

  #pragma unroll
  for (int h2 = 0; h2 < 2; h2++){
    int n = lane + 64*h2;
    const short8* vr = (const short8*)(vb + (size_t)n*768);
    #pragma unroll
    for (int c = 0; c < 4; c++){
      short8 v = vr[c];
      #pragma unroll
      for (int u = 0; u < 8; u++)
        Vt[(c*8+u)*136 + n] = (unsigned short)v[u];
    }
  }
  bf16x8 bk[8];
  #pragma unroll
  for (int j = 0; j < 8; j++)
    bk[j] = *(const bf16x8*)(kb + (size_t)(16*j + fr)*768 + fq*8);
  __syncthreads();
  bf16x8 bv[4][2];
  #pragma unroll
  for (int kk = 0; kk < 4; kk++)
    #pragma unroll
    for (int j2 = 0; j2 < 2; j2++)
      bv[kk][j2] = *(const bf16x8*)&Vt[(16*j2 + fr)*136 + kk*32 + fq*8];

  const float SCALE = 0.17677669529663687f;
  for (int m0 = 0; m0 < 128; m0 += 16){
    bf16x8 aq = *(const bf16x8*)(qb + (size_t)(m0 + fr)*768 + fq*8);
    f32x4 s[8];
    #pragma unroll
    for (int j = 0; j < 8; j++)
      s[j] = __builtin_amdgcn_mfma_f32_16x16x32_bf16(aq, bk[j], f32x4{0.f,0.f,0.f,0.f}, 0, 0, 0);
    float linv[4];
    #pragma unroll
    for (int r = 0; r < 4; r++){
      float mx = s[0][r];
      #pragma unroll
      for (int j = 1; j < 8; j++) mx = fmaxf(mx, s[j][r]);
      mx = fmaxf(mx, __shfl_xor(mx, 1, 64));
      mx = fmaxf(mx, __shfl_xor(mx, 2, 64));
      mx = fmaxf(mx, __shfl_xor(mx, 4, 64));
      mx = fmaxf(mx, __shfl_xor(mx, 8, 64));
      float sum = 0.f;
      #pragma unroll
      for (int j = 0; j < 8; j++){
        float p = __expf((s[j][r] - mx) * SCALE);
        unsigned short pb = f2b(p);
        s[j][r] = b2f(pb);
        sum += s[j][r];
      }
      sum += __shfl_xor(sum, 1, 64);
      sum += __shfl_xor(sum, 2, 64);
      sum += __shfl_xor(sum, 4, 64);
      sum += __shfl_xor(sum, 8, 64);
      linv[r] = 1.f / sum;
    }
    #pragma unroll
    for (int j = 0; j < 8; j++)
      #pragma unroll
      for (int r = 0; r < 4; r++){
        int row = fq*4 + r;
        int col = (16*j + fr) ^ ((row & 7) << 3);
        P[row*128 + col] = f2b(s[j][r]);
      }
    __syncthreads();
    f32x4 o0 = {0.f,0.f,0.f,0.f}, o1 = {0.f,0.f,0.f,0.f};
    #pragma unroll
    for (int kk = 0; kk < 4; kk++){
      bf16x8 pa = *(const bf16x8*)&P[fr*128 + ((kk*32 + fq*8) ^ ((fr & 7) << 3))];
      o0 = __builtin_amdgcn_mfma_f32_16x16x32_bf16(pa, bv[kk][0], o0, 0, 0, 0);
      o1 = __builtin_amdgcn_mfma_f32_16x16x32_bf16(pa, bv[kk][1], o1, 0, 0, 0);
    }
    #pragma unroll
    for (int r = 0; r < 4; r++){
      int row = g*128 + m0 + fq*4 + r;
      unsigned short* dst = o_out + (size_t)row*DD + hh*32;
      dst[fr]      = f2b(o0[r]*linv[r]);
      dst[16 + fr] = f2b(o1[r]*linv[r]);
    }
    __syncthreads();
  }
}

__global__ __launch_bounds__(256) void pool_k(const unsigned short* __restrict__ hb,
                                              float* __restrict__ out){
  int g = blockIdx.x, d = threadIdx.x;
  float acc = 0.f;
  for (int r = 0; r < NPGx; r++) acc += b2f(hb[(size_t)(g*NPGx + r)*DD + d]);
  out[g*DD + d] = acc;
}

// ---------------------------------------------------------------------------

extern "C" void kernel_launch(void* const* d_in, const int* in_sizes, int n_in,
                              void* d_out, int out_size, void* d_ws, size_t ws_size,
                              hipStream_t stream)
{
  const int*   x         = (const int*)  d_in[0];
  const int*   ei        = (const int*)  d_in[1];
  const int*   ea        = (const int*)  d_in[2];
  const float* pe        = (const float*)d_in[4];
  const float* atom_emb  = (const float*)d_in[5];
  const float* bond_emb  = (const float*)d_in[6];
  const float* pe_w      = (const float*)d_in[7];
  const float* pe_b      = (const float*)d_in[8];
  const float* gine_w1   = (const float*)d_in[9];
  const float* gine_b1   = (const float*)d_in[10];
  const float* gine_g1   = (const float*)d_in[11];
  const float* gine_be1  = (const float*)d_in[12];
  const float* gine_w2   = (const float*)d_in[13];
  const float* gine_b2   = (const float*)d_in[14];
  const float* attn_wqkv = (const float*)d_in[15];
  const float* attn_bqkv = (const float*)d_in[16];
  const float* attn_wo   = (const float*)d_in[17];
  const float* attn_bo   = (const float*)d_in[18];
  const float* n1_g      = (const float*)d_in[19];
  const float* n1_b      = (const float*)d_in[20];
  const float* n2_g      = (const float*)d_in[21];
  const float* n2_b      = (const float*)d_in[22];
  const float* n3_g      = (const float*)d_in[23];
  const float* n3_b      = (const float*)d_in[24];
  const float* mlp_w1    = (const float*)d_in[25];
  const float* mlp_b1    = (const float*)d_in[26];
  const float* mlp_w2    = (const float*)d_in[27];
  const float* mlp_b2    = (const float*)d_in[28];
  float* out = (float*)d_out;

  char* wsp = (char*)d_ws;
  size_t off = 0;
  auto alloc = [&](size_t bytes)->void*{
    void* p = wsp + off; off += (bytes + 255) & ~(size_t)255; return p;
  };
  unsigned short* hb  = (unsigned short*)alloc((size_t)NN*DD*2);
  unsigned short* t1  = (unsigned short*)alloc((size_t)NN*DD*2);
  unsigned short* t2  = (unsigned short*)alloc((size_t)NN*DD*2);
  unsigned short* t4  = (unsigned short*)alloc((size_t)NN*DD*2);
  unsigned short* big = (unsigned short*)alloc((size_t)NN*768*2);
  unsigned short* wt  = (unsigned short*)alloc((size_t)LL*655360*2);
  unsigned short* combo = (unsigned short*)alloc((size_t)512*DD*2);
  int*   row_ptr = (int*)  alloc((size_t)(NN+1)*4);
  int*   cursor  = (int*)  alloc((size_t)NN*4);
  int*   slot    = (int*)  alloc((size_t)EE*4);
  float* stats   = (float*)alloc((size_t)LL*4*2*DD*4);
  if (off > ws_size) return;

  hipMemsetAsync(stats,  0, (size_t)LL*4*2*DD*4, stream);
  hipMemsetAsync(cursor, 0, (size_t)NN*4, stream);
  combo_k<<<512, 256, 0, stream>>>(bond_emb, combo);
  twt_k  <<<LL*2304, 256, 0, stream>>>(gine_w1, gine_w2, attn_wqkv, attn_wo,
                                       mlp_w1, mlp_w2, wt);
  hist_k <<<512, 256, 0, stream>>>(ei, cursor);
  scan_k <<<1, 1024, 0, stream>>>(cursor, row_ptr);
  fill_k <<<512, 256, 0, stream>>>(ei, ea, cursor, slot);
  enc_k  <<<NN/4, 256, 0, stream>>>(x, pe, atom_emb, pe_w, pe_b, hb);

  for (int l = 0; l < LL; l++){
    unsigned short* wl = wt + (size_t)l*655360;
    const float* b1   = gine_b1   + l*DD;
    const float* b2   = gine_b2   + l*DD;
    const float* bqkv = attn_bqkv + l*768;
    const float* bo   = attn_bo   + l*DD;
    const float* mb1  = mlp_b1    + l*FFF;
    const float* mb2  = mlp_b2    + l*DD;
    float* S0 = stats + (l*4+0)*2*DD;
    float* S1 = stats + (l*4+1)*2*DD;
    float* S2 = stats + (l*4+2)*2*DD;
    float* S3 = stats + (l*4+3)*2*DD;

    gather_k<<<NN/4, 256, 0, stream>>>(hb, row_ptr, slot, combo, t1);
    // t2 = t1 @ w1 + b1 ; stats S0
    mgemm_k<0,false,false,true><<<dim3(256,1), 512, 0, stream>>>(
        t1, nullptr, wl + 0, b1, nullptr,
        nullptr,nullptr,nullptr, nullptr,nullptr,nullptr, S0, t2, 256, 256);
    // t1 = relu( relu(bn(t2;S0,g1,be1)) @ w2 + b2 ) + hb ; stats S1
    mgemm_k<1,true,true,true><<<dim3(256,1), 512, 0, stream>>>(
        t2, nullptr, wl + 65536, b2, hb,
        S0, gine_g1 + l*DD, gine_be1 + l*DD, nullptr,nullptr,nullptr, S1, t1, 256, 256);
    // big = hb @ wqkv + bqkv
    mgemm_k<0,false,false,false><<<dim3(256,3), 512, 0, stream>>>(
        hb, nullptr, wl + 131072, bqkv, nullptr,
        nullptr,nullptr,nullptr, nullptr,nullptr,nullptr, nullptr, big, 768, 256);
    attn_k<<<GG*8, 64, 0, stream>>>(big, t2);
    // t4 = t2 @ wo + bo + hb ; stats S2
    mgemm_k<0,false,true,true><<<dim3(256,1), 512, 0, stream>>>(
        t2, nullptr, wl + 327680, bo, hb,
        nullptr,nullptr,nullptr, nullptr,nullptr,nullptr, S2, t4, 256, 256);
    // big = relu( (bn(t1;S1,n1)+bn(t4;S2,n2)) @ mw1 + mb1 )
    mgemm_k<2,true,false,false><<<dim3(256,2), 512, 0, stream>>>(
        t1, t4, wl + 393216, mb1, nullptr,
        S1, n1_g + l*DD, n1_b + l*DD, S2, n2_g + l*DD, n2_b + l*DD, nullptr, big, 512, 256);
    // hb = big @ mw2 + mb2 ; stats S3
    mgemm_k<0,false,false,true><<<dim3(256,1), 512, 0, stream>>>(
        big, nullptr, wl + 524288, mb2, nullptr,
        nullptr,nullptr,nullptr, nullptr,nullptr,nullptr, S3, hb, 256, 512);
    bnf_k<<<NN*DD/2048, 256, 0, stream>>>(hb, S3, n3_g + l*DD, n3_b + l*DD);
  }
  pool_k<<<GG, 256, 0, stream>>>(hb, out);
}

// Round 5
// 1653.840 us; speedup vs baseline: 4.2198x; 1.0013x over previous
//
#include <hip/hip_runtime.h>
#include <stdint.h>

// ---------------------------------------------------------------------------
// GPS (GINE + dense MHA + MLP, BatchNorm) forward, MI355X round-5.
// GEMMs: 128x256 tile, BK=32, 8 waves (2x4), 52 KB LDS -> 2-3 blocks/CU
// (TLP hides stage latency). Both-sides XOR chunk swizzle. BN folded into
// GEMM prologues/epilogues. Tiled weight transpose. Register-cached encoder.
// ---------------------------------------------------------------------------

#define NN   65536
#define EE   524288
#define DD   256
#define LL   4
#define GG   512
#define NPGx 128
#define FFF  512

typedef __attribute__((ext_vector_type(8))) short short8;
typedef __attribute__((ext_vector_type(8))) __bf16 bf16x8;
typedef __attribute__((ext_vector_type(4))) float f32x4;

__device__ __forceinline__ float b2f(unsigned short u){
  union {unsigned int i; float f;} z; z.i = ((unsigned int)u) << 16; return z.f;
}
__device__ __forceinline__ unsigned short f2b(float f){
  union {float f; unsigned int i;} z; z.f = f;
  unsigned int r = z.i + 0x7fff + ((z.i >> 16) & 1u);
  return (unsigned short)(r >> 16);
}

__device__ __forceinline__ void gld16(void* lds, const void* g){
  __builtin_amdgcn_global_load_lds(
      (const __attribute__((address_space(1))) void*)g,
      (__attribute__((address_space(3))) void*)lds, 16, 0, 0);
}

// ---------------- preprocessing ----------------

__global__ __launch_bounds__(256) void combo_k(const float* __restrict__ be,
                                               unsigned short* __restrict__ tab){
  int c = blockIdx.x, d = threadIdx.x;
  int a0 = c & 7, a1 = (c >> 3) & 7, a2 = (c >> 6) & 7;
  tab[c*DD + d] = f2b(be[a0*DD + d] + be[(8 + a1)*DD + d] + be[(16 + a2)*DD + d]);
}

__global__ __launch_bounds__(256) void hist_k(const int* __restrict__ ei,
                                              int* __restrict__ cnt){
  for (int i = blockIdx.x*256 + threadIdx.x; i < EE; i += gridDim.x*256)
    atomicAdd(&cnt[ei[EE + i]], 1);
}

__global__ __launch_bounds__(1024) void scan_k(int* __restrict__ cnt,
                                               int* __restrict__ row_ptr){
  __shared__ int sd[1024];
  __shared__ int carry;
  int t = threadIdx.x;
  if (t == 0) carry = 0;
  __syncthreads();
  for (int base = 0; base < NN; base += 4096){
    int idx = base + t*4;
    int v0 = cnt[idx+0], v1 = cnt[idx+1], v2 = cnt[idx+2], v3 = cnt[idx+3];
    int s = v0 + v1 + v2 + v3;
    sd[t] = s; __syncthreads();
    for (int offd = 1; offd < 1024; offd <<= 1){
      int xv = (t >= offd) ? sd[t - offd] : 0;
      __syncthreads();
      sd[t] += xv;
      __syncthreads();
    }
    int excl = sd[t] - s + carry;
    row_ptr[idx+0] = excl;             cnt[idx+0] = excl;
    row_ptr[idx+1] = excl + v0;        cnt[idx+1] = excl + v0;
    row_ptr[idx+2] = excl + v0 + v1;   cnt[idx+2] = excl + v0 + v1;
    row_ptr[idx+3] = excl + v0+v1+v2;  cnt[idx+3] = excl + v0+v1+v2;
    __syncthreads();
    if (t == 0) carry += sd[1023];
    __syncthreads();
  }
  if (t == 0) row_ptr[NN] = carry;
}

__global__ __launch_bounds__(256) void fill_k(const int* __restrict__ ei,
                                              const int* __restrict__ ea,
                                              int* __restrict__ cursor,
                                              int* __restrict__ slot){
  for (int i = blockIdx.x*256 + threadIdx.x; i < EE; i += gridDim.x*256){
    int s  = ei[i];
    int dn = ei[EE + i];
    int a0 = ea[i*3+0], a1 = ea[i*3+1], a2 = ea[i*3+2];
    int cb = a0 | (a1 << 3) | (a2 << 6);
    int p = atomicAdd(&cursor[dn], 1);
    slot[p] = s | (cb << 16);
  }
}

// tiled weight transpose + bf16: 64x64 tiles via LDS, coalesced both sides
__global__ __launch_bounds__(256) void twt_k(const float* __restrict__ w1,
                                             const float* __restrict__ w2,
                                             const float* __restrict__ wqkv,
                                             const float* __restrict__ wo,
                                             const float* __restrict__ m1,
                                             const float* __restrict__ m2,
                                             unsigned short* __restrict__ wt){
  __shared__ float tile[64][65];
  int l = blockIdx.x / 160;
  int r = blockIdx.x % 160;
  const float* src; unsigned short* dst; int K, Nsrc, t0;
  unsigned short* wl = wt + (size_t)l*655360;
  if (r < 16)      { src = w1  +(size_t)l*65536;  dst = wl;        K=256; Nsrc=256; t0=r; }
  else if (r < 32) { src = w2  +(size_t)l*65536;  dst = wl+65536;  K=256; Nsrc=256; t0=r-16; }
  else if (r < 80) { src = wqkv+(size_t)l*196608; dst = wl+131072; K=256; Nsrc=768; t0=r-32; }
  else if (r < 96) { src = wo  +(size_t)l*65536;  dst = wl+327680; K=256; Nsrc=256; t0=r-80; }
  else if (r < 128){ src = m1  +(size_t)l*131072; dst = wl+393216; K=256; Nsrc=512; t0=r-96; }
  else             { src = m2  +(size_t)l*131072; dst = wl+524288; K=512; Nsrc=256; t0=r-128; }
  int nkt = K >> 6;
  int tn = t0 / nkt, tk = t0 % nkt;
  int rr = threadIdx.x >> 6, cc = threadIdx.x & 63;
  for (int p = 0; p < 64; p += 4)
    tile[p+rr][cc] = src[(size_t)(tk*64 + p + rr)*Nsrc + tn*64 + cc];
  __syncthreads();
  for (int p = 0; p < 64; p += 4)
    dst[(size_t)(tn*64 + p + rr)*K + tk*64 + cc] = f2b(tile[cc][p+rr]);
}

// AtomEncoder + PE: wave owns d-slice (f32x4), 8 nodes/wave, pe_w in registers
__global__ __launch_bounds__(256) void enc_k(const int* __restrict__ x,
                                             const float* __restrict__ pe,
                                             const float* __restrict__ atom_emb,
                                             const float* __restrict__ pe_w,
                                             const float* __restrict__ pe_b,
                                             unsigned short* __restrict__ hb){
  int wv = blockIdx.x*4 + (threadIdx.x >> 6);
  int lane = threadIdx.x & 63;
  int d0 = lane*4;
  f32x4 pw[20];
  #pragma unroll
  for (int t = 0; t < 20; t++) pw[t] = *(const f32x4*)(pe_w + t*DD + d0);
  f32x4 pb = *(const f32x4*)(pe_b + d0);
  int n0 = wv*8;
  for (int n = n0; n < n0 + 8; n++){
    f32x4 acc = pb;
    #pragma unroll
    for (int i = 0; i < 9; i++){
      int xi = x[n*9 + i];
      acc += *(const f32x4*)(atom_emb + (size_t)(i*128 + xi)*DD + d0);
    }
    #pragma unroll
    for (int t = 0; t < 20; t++) acc += pe[n*20 + t] * pw[t];
    ushort4 o;
    o.x = f2b(acc[0]); o.y = f2b(acc[1]); o.z = f2b(acc[2]); o.w = f2b(acc[3]);
    *(ushort4*)(hb + (size_t)n*DD + d0) = o;
  }
}

// GINE gather: wave per node, 2 edges/iteration
__global__ __launch_bounds__(256) void gather_k(const unsigned short* __restrict__ hb,
                                                const int* __restrict__ row_ptr,
                                                const int* __restrict__ slot,
                                                const unsigned short* __restrict__ combo,
                                                unsigned short* __restrict__ t1){
  int w = threadIdx.x >> 6, lane = threadIdx.x & 63;
  int n = blockIdx.x*4 + w;
  int half = lane >> 5, l32 = lane & 31;
  int d0 = l32*8;
  int beg = row_ptr[n], end = row_ptr[n+1];
  float acc[8];
  #pragma unroll
  for (int u = 0; u < 8; u++) acc[u] = 0.f;
  for (int e = beg + half; e < end; e += 2){
    int s = slot[e];
    int src = s & 0xFFFF;
    int cb  = ((unsigned)s) >> 16;
    short8 hv = *(const short8*)(hb + (size_t)src*DD + d0);
    short8 cv = *(const short8*)(combo + (size_t)cb*DD + d0);
    #pragma unroll
    for (int u = 0; u < 8; u++)
      acc[u] += fmaxf(b2f((unsigned short)hv[u]) + b2f((unsigned short)cv[u]), 0.f);
  }
  #pragma unroll
  for (int u = 0; u < 8; u++) acc[u] += __shfl_xor(acc[u], 32, 64);
  if (half == 0){
    short8 hn = *(const short8*)(hb + (size_t)n*DD + d0);
    short8 o;
    #pragma unroll
    for (int u = 0; u < 8; u++) o[u] = (short)f2b(b2f((unsigned short)hn[u]) + acc[u]);
    *(short8*)(t1 + (size_t)n*DD + d0) = o;
  }
}

// ---------------- MFMA GEMM: 128x256 tile, 8 waves, BK=32, dbuf ------------
// PRO 0: A staged via global_load_lds (pre-swizzled source)
// PRO 1: A = relu(bn(A; st1,g1,b1))  (reg-staged, swizzled ds_write)
// PRO 2: A = bn(A;st1,g1,b1) + bn(A2;st2,g2,b2)
template<int PRO, bool RELU, bool RES, bool STATS>
__global__ __launch_bounds__(512, 4) void mgemm_k(
    const unsigned short* __restrict__ A,
    const unsigned short* __restrict__ A2,
    const unsigned short* __restrict__ Bt,
    const float* __restrict__ bias,
    const unsigned short* __restrict__ res,
    const float* __restrict__ stIn1, const float* __restrict__ gg1, const float* __restrict__ bb1,
    const float* __restrict__ stIn2, const float* __restrict__ gg2, const float* __restrict__ bb2,
    float* __restrict__ statsOut,
    unsigned short* __restrict__ C,
    int Nn, int K)
{
  __shared__ __align__(16) __bf16 SA[2][128*32];     // 16 KB
  __shared__ __align__(16) __bf16 SB[2][256*32];     // 32 KB
  __shared__ __align__(16) float scF1[256], shF1[256], scF2[256], shF2[256];

  const int tid  = threadIdx.x;
  const int wid  = tid >> 6, lane = tid & 63;
  const int row0 = blockIdx.x * 128, col0 = blockIdx.y * 256;
  const int wrr = wid >> 2, wcc = wid & 3;           // wave tile: 64 rows x 64 cols
  const int fr = lane & 15, fq = lane >> 4;
  const int srow = tid >> 2, sch = tid & 3;          // staging: row, chunk
  const int swc = sch ^ (srow & 3);                  // pre-swizzled source chunk
  const int nt = K >> 5;

  if (PRO >= 1 && tid < 256){
    float mu = stIn1[tid]*(1.f/NN);
    float var = stIn1[256+tid]*(1.f/NN) - mu*mu;
    float s = rsqrtf(var + 1e-5f) * gg1[tid];
    scF1[tid] = s; shF1[tid] = bb1[tid] - mu*s;
    if (PRO == 2){
      float mu2 = stIn2[tid]*(1.f/NN);
      float va2 = stIn2[256+tid]*(1.f/NN) - mu2*mu2;
      float s2 = rsqrtf(va2 + 1e-5f) * gg2[tid];
      scF2[tid] = s2; shF2[tid] = bb2[tid] - mu2*s2;
    }
  }

  f32x4 acc[4][4];
  #pragma unroll
  for (int i = 0; i < 4; i++)
    #pragma unroll
    for (int j = 0; j < 4; j++) acc[i][j] = f32x4{0.f,0.f,0.f,0.f};

  auto stageA = [&](int buf, int kt){
    gld16(&SA[buf][(wid*16)*32],
          A + (size_t)(row0 + srow)*K + kt + swc*8);
  };
  auto stageB = [&](int buf, int kt){
    #pragma unroll
    for (int rr = 0; rr < 2; rr++)
      gld16(&SB[buf][(wid*16 + rr*128)*32],
            Bt + (size_t)(col0 + srow + rr*128)*K + kt + swc*8);
  };

  short8 g1v, g4v;
  auto loadA = [&](int kt){
    g1v = *(const short8*)(A + (size_t)(row0 + srow)*K + kt + sch*8);
    if (PRO == 2) g4v = *(const short8*)(A2 + (size_t)(row0 + srow)*K + kt + sch*8);
  };
  auto dswA = [&](int buf, int kt){
    f32x4 s1a = *(const f32x4*)&scF1[kt + sch*8];
    f32x4 s1b = *(const f32x4*)&scF1[kt + sch*8 + 4];
    f32x4 h1a = *(const f32x4*)&shF1[kt + sch*8];
    f32x4 h1b = *(const f32x4*)&shF1[kt + sch*8 + 4];
    f32x4 s2a, s2b, h2a, h2b;
    if (PRO == 2){
      s2a = *(const f32x4*)&scF2[kt + sch*8];
      s2b = *(const f32x4*)&scF2[kt + sch*8 + 4];
      h2a = *(const f32x4*)&shF2[kt + sch*8];
      h2b = *(const f32x4*)&shF2[kt + sch*8 + 4];
    }
    short8 o;
    #pragma unroll
    for (int u = 0; u < 8; u++){
      float sc = (u < 4) ? s1a[u&3] : s1b[u&3];
      float sh = (u < 4) ? h1a[u&3] : h1b[u&3];
      float v = b2f((unsigned short)g1v[u]) * sc + sh;
      if (PRO == 1) v = fmaxf(v, 0.f);
      if (PRO == 2){
        float sc2 = (u < 4) ? s2a[u&3] : s2b[u&3];
        float sh2 = (u < 4) ? h2a[u&3] : h2b[u&3];
        v += b2f((unsigned short)g4v[u]) * sc2 + sh2;
      }
      o[u] = (short)f2b(v);
    }
    *(short8*)&SA[buf][srow*32 + swc*8] = o;
  };

  // prologue
  if (PRO == 0){
    stageA(0, 0); stageB(0, 0);
  } else {
    loadA(0); stageB(0, 0);
    __syncthreads();                 // scF/shF visible before first dswA
  }

  // K loop: stage(t+1) overlaps compute(t); one barrier per K-step
  int cur = 0;
  for (int t = 0; t < nt; t++){
    if (PRO == 0){
      __syncthreads();
      if (t+1 < nt){ stageA(cur^1, (t+1)*32); stageB(cur^1, (t+1)*32); }
    } else {
      dswA(cur, t*32);
      __syncthreads();
      if (t+1 < nt){ loadA((t+1)*32); stageB(cur^1, (t+1)*32); }
    }
    {
      int kc = (fq ^ (fr & 3)) * 8;
      bf16x8 a[4], b[4];
      #pragma unroll
      for (int i = 0; i < 4; i++)
        a[i] = *(const bf16x8*)&SA[cur][(wrr*64 + 16*i + fr)*32 + kc];
      #pragma unroll
      for (int j = 0; j < 4; j++)
        b[j] = *(const bf16x8*)&SB[cur][(wcc*64 + 16*j + fr)*32 + kc];
      #pragma unroll
      for (int i = 0; i < 4; i++)
        #pragma unroll
        for (int j = 0; j < 4; j++)
          acc[i][j] = __builtin_amdgcn_mfma_f32_16x16x32_bf16(a[i], b[j], acc[i][j], 0, 0, 0);
    }
    cur ^= 1;
  }

  // epilogue
  float bj[4];
  #pragma unroll
  for (int j = 0; j < 4; j++) bj[j] = bias[col0 + wcc*64 + 16*j + fr];

  #pragma unroll
  for (int i = 0; i < 4; i++){
    #pragma unroll
    for (int j = 0; j < 4; j++){
      int col = col0 + wcc*64 + 16*j + fr;
      #pragma unroll
      for (int r = 0; r < 4; r++){
        int row = row0 + wrr*64 + 16*i + fq*4 + r;
        float y = acc[i][j][r] + bj[j];
        if constexpr (RELU) y = fmaxf(y, 0.f);
        if constexpr (RES)  y += b2f(res[(size_t)row*256 + col]);
        acc[i][j][r] = y;
        C[(size_t)row*Nn + col] = f2b(y);
      }
    }
  }

  if constexpr (STATS){
    float* csA = (float*)&SA[0][0];          // SA is dead; reuse as stats scratch
    float* cqA = csA + 256;
    __syncthreads();                          // all SA reads complete
    if (tid < 256){ csA[tid] = 0.f; cqA[tid] = 0.f; }
    __syncthreads();
    #pragma unroll
    for (int j = 0; j < 4; j++){
      float ps = 0.f, pq = 0.f;
      #pragma unroll
      for (int i = 0; i < 4; i++)
        #pragma unroll
        for (int r = 0; r < 4; r++){ float v = acc[i][j][r]; ps += v; pq += v*v; }
      ps += __shfl_xor(ps, 16, 64); pq += __shfl_xor(pq, 16, 64);
      ps += __shfl_xor(ps, 32, 64); pq += __shfl_xor(pq, 32, 64);
      if (lane < 16){
        atomicAdd(&csA[wcc*64 + 16*j + fr], ps);
        atomicAdd(&cqA[wcc*64 + 16*j + fr], pq);
      }
    }
    __syncthreads();
    if (tid < 256){
      atomicAdd(&statsOut[col0 + tid],       csA[tid]);
      atomicAdd(&statsOut[256 + col0 + tid], cqA[tid]);
    }
  }
}

// in-place BN apply (post-mlp2)
__global__ __launch_bounds__(256) void bnf_k(unsigned short* __restrict__ t,
                                             const float* __restrict__ st,
                                             const float* __restrict__ g,
                                             const float* __restrict__ b){
  __shared__ float sc[256], sh[256];
  int tid = threadIdx.x;
  {
    float mu  = st[tid] * (1.f/NN);
    float var = st[256+tid] * (1.f/NN) - mu*mu;
    float s   = rsqrtf(var + 1e-5f) * g[tid];
    sc[tid] = s; sh[tid] = b[tid] - mu*s;
  }
  __syncthreads();
  size_t base = ((size_t)blockIdx.x*256 + tid)*8;
  int c0 = (int)(base & 255);
  short8 v = *(const short8*)(t + base);
  short8 o;
  #pragma unroll
  for (int u = 0; u < 8; u++){
    float f = b2f((unsigned short)v[u])*sc[c0+u] + sh[c0+u];
    o[u] = (short)f2b(f);
  }
  *(short8*)(t + base) = o;
}

// ---------------- MFMA attention (verified round-3) ----------------
__global__ __launch_bounds__(64) void attn_k(const unsigned short* __restrict__ qkv,
                                             unsigned short* __restrict__ o_out){
  int g  = blockIdx.x >> 3;
  int hh = blockIdx.x & 7;
  int lane = threadIdx.x;
  int fr = lane & 15, fq = lane >> 4;
  __shared__ __align__(16) unsigned short Vt[32*136];
  __shared__ __align__(16) unsigned short P[16*128];

  const unsigned short* qb = qkv + (size_t)g*128*768 + hh*32;
  const unsigned short* kb = qb + 256;
  const unsigned short* vb = qb + 512;

  #pragma unroll
  for (int h2 = 0; h2 < 2; h2++){
    int n = lane + 64*h2;
    const short8* vr = (const short8*)(vb + (size_t)n*768);
    #pragma unroll
    for (int c = 0; c < 4; c++){
      short8 v = vr[c];
      #pragma unroll
      for (int u = 0; u < 8; u++)
        Vt[(c*8+u)*136 + n] = (unsigned short)v[u];
    }
  }
  bf16x8 bk[8];
  #pragma unroll
  for (int j = 0; j < 8; j++)
    bk[j] = *(const bf16x8*)(kb + (size_t)(16*j + fr)*768 + fq*8);
  __syncthreads();
  bf16x8 bv[4][2];
  #pragma unroll
  for (int kk = 0; kk < 4; kk++)
    #pragma unroll
    for (int j2 = 0; j2 < 2; j2++)
      bv[kk][j2] = *(const bf16x8*)&Vt[(16*j2 + fr)*136 + kk*32 + fq*8];

  const float SCALE = 0.17677669529663687f;
  for (int m0 = 0; m0 < 128; m0 += 16){
    bf16x8 aq = *(const bf16x8*)(qb + (size_t)(m0 + fr)*768 + fq*8);
    f32x4 s[8];
    #pragma unroll
    for (int j = 0; j < 8; j++)
      s[j] = __builtin_amdgcn_mfma_f32_16x16x32_bf16(aq, bk[j], f32x4{0.f,0.f,0.f,0.f}, 0, 0, 0);
    float linv[4];
    #pragma unroll
    for (int r = 0; r < 4; r++){
      float mx = s[0][r];
      #pragma unroll
      for (int j = 1; j < 8; j++) mx = fmaxf(mx, s[j][r]);
      mx = fmaxf(mx, __shfl_xor(mx, 1, 64));
      mx = fmaxf(mx, __shfl_xor(mx, 2, 64));
      mx = fmaxf(mx, __shfl_xor(mx, 4, 64));
      mx = fmaxf(mx, __shfl_xor(mx, 8, 64));
      float sum = 0.f;
      #pragma unroll
      for (int j = 0; j < 8; j++){
        float p = __expf((s[j][r] - mx) * SCALE);
        unsigned short pb = f2b(p);
        s[j][r] = b2f(pb);
        sum += s[j][r];
      }
      sum += __shfl_xor(sum, 1, 64);
      sum += __shfl_xor(sum, 2, 64);
      sum += __shfl_xor(sum, 4, 64);
      sum += __shfl_xor(sum, 8, 64);
      linv[r] = 1.f / sum;
    }
    #pragma unroll
    for (int j = 0; j < 8; j++)
      #pragma unroll
      for (int r = 0; r < 4; r++){
        int row = fq*4 + r;
        int col = (16*j + fr) ^ ((row & 7) << 3);
        P[row*128 + col] = f2b(s[j][r]);
      }
    __syncthreads();
    f32x4 o0 = {0.f,0.f,0.f,0.f}, o1 = {0.f,0.f,0.f,0.f};
    #pragma unroll
    for (int kk = 0; kk < 4; kk++){
      bf16x8 pa = *(const bf16x8*)&P[fr*128 + ((kk*32 + fq*8) ^ ((fr & 7) << 3))];
      o0 = __builtin_amdgcn_mfma_f32_16x16x32_bf16(pa, bv[kk][0], o0, 0, 0, 0);
      o1 = __builtin_amdgcn_mfma_f32_16x16x32_bf16(pa, bv[kk][1], o1, 0, 0, 0);
    }
    #pragma unroll
    for (int r = 0; r < 4; r++){
      int row = g*128 + m0 + fq*4 + r;
      unsigned short* dst = o_out + (size_t)row*DD + hh*32;
      dst[fr]      = f2b(o0[r]*linv[r]);
      dst[16 + fr] = f2b(o1[r]*linv[r]);
    }
    __syncthreads();
  }
}

__global__ __launch_bounds__(256) void pool_k(const unsigned short* __restrict__ hb,
                                              float* __restrict__ out){
  int g = blockIdx.x, d = threadIdx.x;
  float acc = 0.f;
  for (int r = 0; r < NPGx; r++) acc += b2f(hb[(size_t)(g*NPGx + r)*DD + d]);
  out[g*DD + d] = acc;
}

// ---------------------------------------------------------------------------

extern "C" void kernel_launch(void* const* d_in, const int* in_sizes, int n_in,
                              void* d_out, int out_size, void* d_ws, size_t ws_size,
                              hipStream_t stream)
{
  const int*   x         = (const int*)  d_in[0];
  const int*   ei        = (const int*)  d_in[1];
  const int*   ea        = (const int*)  d_in[2];
  const float* pe        = (const float*)d_in[4];
  const float* atom_emb  = (const float*)d_in[5];
  const float* bond_emb  = (const float*)d_in[6];
  const float* pe_w      = (const float*)d_in[7];
  const float* pe_b      = (const float*)d_in[8];
  const float* gine_w1   = (const float*)d_in[9];
  const float* gine_b1   = (const float*)d_in[10];
  const float* gine_g1   = (const float*)d_in[11];
  const float* gine_be1  = (const float*)d_in[12];
  const float* gine_w2   = (const float*)d_in[13];
  const float* gine_b2   = (const float*)d_in[14];
  const float* attn_wqkv = (const float*)d_in[15];
  const float* attn_bqkv = (const float*)d_in[16];
  const float* attn_wo   = (const float*)d_in[17];
  const float* attn_bo   = (const float*)d_in[18];
  const float* n1_g      = (const float*)d_in[19];
  const float* n1_b      = (const float*)d_in[20];
  const float* n2_g      = (const float*)d_in[21];
  const float* n2_b      = (const float*)d_in[22];
  const float* n3_g      = (const float*)d_in[23];
  const float* n3_b      = (const float*)d_in[24];
  const float* mlp_w1    = (const float*)d_in[25];
  const float* mlp_b1    = (const float*)d_in[26];
  const float* mlp_w2    = (const float*)d_in[27];
  const float* mlp_b2    = (const float*)d_in[28];
  float* out = (float*)d_out;

  char* wsp = (char*)d_ws;
  size_t off = 0;
  auto alloc = [&](size_t bytes)->void*{
    void* p = wsp + off; off += (bytes + 255) & ~(size_t)255; return p;
  };
  unsigned short* hb  = (unsigned short*)alloc((size_t)NN*DD*2);
  unsigned short* t1  = (unsigned short*)alloc((size_t)NN*DD*2);
  unsigned short* t2  = (unsigned short*)alloc((size_t)NN*DD*2);
  unsigned short* t4  = (unsigned short*)alloc((size_t)NN*DD*2);
  unsigned short* big = (unsigned short*)alloc((size_t)NN*768*2);
  unsigned short* wt  = (unsigned short*)alloc((size_t)LL*655360*2);
  unsigned short* combo = (unsigned short*)alloc((size_t)512*DD*2);
  int*   row_ptr = (int*)  alloc((size_t)(NN+1)*4);
  int*   cursor  = (int*)  alloc((size_t)NN*4);
  int*   slot    = (int*)  alloc((size_t)EE*4);
  float* stats   = (float*)alloc((size_t)LL*4*2*DD*4);
  if (off > ws_size) return;

  hipMemsetAsync(stats,  0, (size_t)LL*4*2*DD*4, stream);
  hipMemsetAsync(cursor, 0, (size_t)NN*4, stream);
  combo_k<<<512, 256, 0, stream>>>(bond_emb, combo);
  twt_k  <<<LL*160, 256, 0, stream>>>(gine_w1, gine_w2, attn_wqkv, attn_wo,
                                      mlp_w1, mlp_w2, wt);
  hist_k <<<512, 256, 0, stream>>>(ei, cursor);
  scan_k <<<1, 1024, 0, stream>>>(cursor, row_ptr);
  fill_k <<<512, 256, 0, stream>>>(ei, ea, cursor, slot);
  enc_k  <<<2048, 256, 0, stream>>>(x, pe, atom_emb, pe_w, pe_b, hb);

  for (int l = 0; l < LL; l++){
    unsigned short* wl = wt + (size_t)l*655360;
    const float* b1   = gine_b1   + l*DD;
    const float* b2   = gine_b2   + l*DD;
    const float* bqkv = attn_bqkv + l*768;
    const float* bo   = attn_bo   + l*DD;
    const float* mb1  = mlp_b1    + l*FFF;
    const float* mb2  = mlp_b2    + l*DD;
    float* S0 = stats + (l*4+0)*2*DD;
    float* S1 = stats + (l*4+1)*2*DD;
    float* S2 = stats + (l*4+2)*2*DD;
    float* S3 = stats + (l*4+3)*2*DD;

    gather_k<<<NN/4, 256, 0, stream>>>(hb, row_ptr, slot, combo, t1);
    // t2 = t1 @ w1 + b1 ; stats S0
    mgemm_k<0,false,false,true><<<dim3(512,1), 512, 0, stream>>>(
        t1, nullptr, wl + 0, b1, nullptr,
        nullptr,nullptr,nullptr, nullptr,nullptr,nullptr, S0, t2, 256, 256);
    // t1 = relu( relu(bn(t2;S0,g1,be1)) @ w2 + b2 ) + hb ; stats S1
    mgemm_k<1,true,true,true><<<dim3(512,1), 512, 0, stream>>>(
        t2, nullptr, wl + 65536, b2, hb,
        S0, gine_g1 + l*DD, gine_be1 + l*DD, nullptr,nullptr,nullptr, S1, t1, 256, 256);
    // big = hb @ wqkv + bqkv
    mgemm_k<0,false,false,false><<<dim3(512,3), 512, 0, stream>>>(
        hb, nullptr, wl + 131072, bqkv, nullptr,
        nullptr,nullptr,nullptr, nullptr,nullptr,nullptr, nullptr, big, 768, 256);
    attn_k<<<GG*8, 64, 0, stream>>>(big, t2);
    // t4 = t2 @ wo + bo + hb ; stats S2
    mgemm_k<0,false,true,true><<<dim3(512,1), 512, 0, stream>>>(
        t2, nullptr, wl + 327680, bo, hb,
        nullptr,nullptr,nullptr, nullptr,nullptr,nullptr, S2, t4, 256, 256);
    // big = relu( (bn(t1;S1,n1)+bn(t4;S2,n2)) @ mw1 + mb1 )
    mgemm_k<2,true,false,false><<<dim3(512,2), 512, 0, stream>>>(
        t1, t4, wl + 393216, mb1, nullptr,
        S1, n1_g + l*DD, n1_b + l*DD, S2, n2_g + l*DD, n2_b + l*DD, nullptr, big, 512, 256);
    // hb = big @ mw2 + mb2 ; stats S3
    mgemm_k<0,false,false,true><<<dim3(512,1), 512, 0, stream>>>(
        big, nullptr, wl + 524288, mb2, nullptr,
        nullptr,nullptr,nullptr, nullptr,nullptr,nullptr, S3, hb, 256, 512);
    bnf_k<<<NN*DD/2048, 256, 0, stream>>>(hb, S3, n3_g + l*DD, n3_b + l*DD);
  }
  pool_k<<<GG, 256, 0, stream>>>(hb, out);
}

// Round 7
// 1573.073 us; speedup vs baseline: 4.4364x; 1.0513x over previous
//
#include <hip/hip_runtime.h>
#include <stdint.h>

// ---------------------------------------------------------------------------
// GPS (GINE + dense MHA + MLP, BatchNorm) forward, MI355X round-6 (resubmit;
// round-6 bench never ran: GPU acquisition timeout).
// mgemm PRO0: 3-buffer pipeline, counted vmcnt(3) + raw barrier (T3/T4).
// attn: 4 heads per block (4 waves), zero barriers. gather: 2x unroll.
// ---------------------------------------------------------------------------

#define NN   65536
#define EE   524288
#define DD   256
#define LL   4
#define GG   512
#define NPGx 128
#define FFF  512

typedef __attribute__((ext_vector_type(8))) short short8;
typedef __attribute__((ext_vector_type(8))) __bf16 bf16x8;
typedef __attribute__((ext_vector_type(4))) float f32x4;

__device__ __forceinline__ float b2f(unsigned short u){
  union {unsigned int i; float f;} z; z.i = ((unsigned int)u) << 16; return z.f;
}
__device__ __forceinline__ unsigned short f2b(float f){
  union {float f; unsigned int i;} z; z.f = f;
  unsigned int r = z.i + 0x7fff + ((z.i >> 16) & 1u);
  return (unsigned short)(r >> 16);
}

__device__ __forceinline__ void gld16(void* lds, const void* g){
  __builtin_amdgcn_global_load_lds(
      (const __attribute__((address_space(1))) void*)g,
      (__attribute__((address_space(3))) void*)lds, 16, 0, 0);
}

// ---------------- preprocessing ----------------

__global__ __launch_bounds__(256) void combo_k(const float* __restrict__ be,
                                               unsigned short* __restrict__ tab){
  int c = blockIdx.x, d = threadIdx.x;
  int a0 = c & 7, a1 = (c >> 3) & 7, a2 = (c >> 6) & 7;
  tab[c*DD + d] = f2b(be[a0*DD + d] + be[(8 + a1)*DD + d] + be[(16 + a2)*DD + d]);
}

__global__ __launch_bounds__(256) void hist_k(const int* __restrict__ ei,
                                              int* __restrict__ cnt){
  for (int i = blockIdx.x*256 + threadIdx.x; i < EE; i += gridDim.x*256)
    atomicAdd(&cnt[ei[EE + i]], 1);
}

__global__ __launch_bounds__(1024) void scan_k(int* __restrict__ cnt,
                                               int* __restrict__ row_ptr){
  __shared__ int sd[1024];
  __shared__ int carry;
  int t = threadIdx.x;
  if (t == 0) carry = 0;
  __syncthreads();
  for (int base = 0; base < NN; base += 4096){
    int idx = base + t*4;
    int v0 = cnt[idx+0], v1 = cnt[idx+1], v2 = cnt[idx+2], v3 = cnt[idx+3];
    int s = v0 + v1 + v2 + v3;
    sd[t] = s; __syncthreads();
    for (int offd = 1; offd < 1024; offd <<= 1){
      int xv = (t >= offd) ? sd[t - offd] : 0;
      __syncthreads();
      sd[t] += xv;
      __syncthreads();
    }
    int excl = sd[t] - s + carry;
    row_ptr[idx+0] = excl;             cnt[idx+0] = excl;
    row_ptr[idx+1] = excl + v0;        cnt[idx+1] = excl + v0;
    row_ptr[idx+2] = excl + v0 + v1;   cnt[idx+2] = excl + v0 + v1;
    row_ptr[idx+3] = excl + v0+v1+v2;  cnt[idx+3] = excl + v0+v1+v2;
    __syncthreads();
    if (t == 0) carry += sd[1023];
    __syncthreads();
  }
  if (t == 0) row_ptr[NN] = carry;
}

__global__ __launch_bounds__(256) void fill_k(const int* __restrict__ ei,
                                              const int* __restrict__ ea,
                                              int* __restrict__ cursor,
                                              int* __restrict__ slot){
  for (int i = blockIdx.x*256 + threadIdx.x; i < EE; i += gridDim.x*256){
    int s  = ei[i];
    int dn = ei[EE + i];
    int a0 = ea[i*3+0], a1 = ea[i*3+1], a2 = ea[i*3+2];
    int cb = a0 | (a1 << 3) | (a2 << 6);
    int p = atomicAdd(&cursor[dn], 1);
    slot[p] = s | (cb << 16);
  }
}

// tiled weight transpose + bf16: 64x64 tiles via LDS
__global__ __launch_bounds__(256) void twt_k(const float* __restrict__ w1,
                                             const float* __restrict__ w2,
                                             const float* __restrict__ wqkv,
                                             const float* __restrict__ wo,
                                             const float* __restrict__ m1,
                                             const float* __restrict__ m2,
                                             unsigned short* __restrict__ wt){
  __shared__ float tile[64][65];
  int l = blockIdx.x / 160;
  int r = blockIdx.x % 160;
  const float* src; unsigned short* dst; int K, Nsrc, t0;
  unsigned short* wl = wt + (size_t)l*655360;
  if (r < 16)      { src = w1  +(size_t)l*65536;  dst = wl;        K=256; Nsrc=256; t0=r; }
  else if (r < 32) { src = w2  +(size_t)l*65536;  dst = wl+65536;  K=256; Nsrc=256; t0=r-16; }
  else if (r < 80) { src = wqkv+(size_t)l*196608; dst = wl+131072; K=256; Nsrc=768; t0=r-32; }
  else if (r < 96) { src = wo  +(size_t)l*65536;  dst = wl+327680; K=256; Nsrc=256; t0=r-80; }
  else if (r < 128){ src = m1  +(size_t)l*131072; dst = wl+393216; K=256; Nsrc=512; t0=r-96; }
  else             { src = m2  +(size_t)l*131072; dst = wl+524288; K=512; Nsrc=256; t0=r-128; }
  int nkt = K >> 6;
  int tn = t0 / nkt, tk = t0 % nkt;
  int rr = threadIdx.x >> 6, cc = threadIdx.x & 63;
  for (int p = 0; p < 64; p += 4)
    tile[p+rr][cc] = src[(size_t)(tk*64 + p + rr)*Nsrc + tn*64 + cc];
  __syncthreads();
  for (int p = 0; p < 64; p += 4)
    dst[(size_t)(tn*64 + p + rr)*K + tk*64 + cc] = f2b(tile[cc][p+rr]);
}

// AtomEncoder + PE: wave owns d-slice, 8 nodes/wave, pe_w in registers
__global__ __launch_bounds__(256) void enc_k(const int* __restrict__ x,
                                             const float* __restrict__ pe,
                                             const float* __restrict__ atom_emb,
                                             const float* __restrict__ pe_w,
                                             const float* __restrict__ pe_b,
                                             unsigned short* __restrict__ hb){
  int wv = blockIdx.x*4 + (threadIdx.x >> 6);
  int lane = threadIdx.x & 63;
  int d0 = lane*4;
  f32x4 pw[20];
  #pragma unroll
  for (int t = 0; t < 20; t++) pw[t] = *(const f32x4*)(pe_w + t*DD + d0);
  f32x4 pb = *(const f32x4*)(pe_b + d0);
  int n0 = wv*8;
  for (int n = n0; n < n0 + 8; n++){
    f32x4 acc = pb;
    #pragma unroll
    for (int i = 0; i < 9; i++){
      int xi = x[n*9 + i];
      acc += *(const f32x4*)(atom_emb + (size_t)(i*128 + xi)*DD + d0);
    }
    #pragma unroll
    for (int t = 0; t < 20; t++) acc += pe[n*20 + t] * pw[t];
    ushort4 o;
    o.x = f2b(acc[0]); o.y = f2b(acc[1]); o.z = f2b(acc[2]); o.w = f2b(acc[3]);
    *(ushort4*)(hb + (size_t)n*DD + d0) = o;
  }
}

// GINE gather: wave per node, 2 edges/iter, unrolled 2x (4 gathers in flight)
__global__ __launch_bounds__(256) void gather_k(const unsigned short* __restrict__ hb,
                                                const int* __restrict__ row_ptr,
                                                const int* __restrict__ slot,
                                                const unsigned short* __restrict__ combo,
                                                unsigned short* __restrict__ t1){
  int w = threadIdx.x >> 6, lane = threadIdx.x & 63;
  int n = blockIdx.x*4 + w;
  int half = lane >> 5, l32 = lane & 31;
  int d0 = l32*8;
  int beg = row_ptr[n], end = row_ptr[n+1];
  float acc[8];
  #pragma unroll
  for (int u = 0; u < 8; u++) acc[u] = 0.f;
  int e = beg + half;
  for (; e + 2 < end; e += 4){
    int sA = slot[e], sB = slot[e+2];
    short8 hvA = *(const short8*)(hb + (size_t)(sA & 0xFFFF)*DD + d0);
    short8 cvA = *(const short8*)(combo + (size_t)(((unsigned)sA) >> 16)*DD + d0);
    short8 hvB = *(const short8*)(hb + (size_t)(sB & 0xFFFF)*DD + d0);
    short8 cvB = *(const short8*)(combo + (size_t)(((unsigned)sB) >> 16)*DD + d0);
    #pragma unroll
    for (int u = 0; u < 8; u++)
      acc[u] += fmaxf(b2f((unsigned short)hvA[u]) + b2f((unsigned short)cvA[u]), 0.f);
    #pragma unroll
    for (int u = 0; u < 8; u++)
      acc[u] += fmaxf(b2f((unsigned short)hvB[u]) + b2f((unsigned short)cvB[u]), 0.f);
  }
  for (; e < end; e += 2){
    int s = slot[e];
    short8 hv = *(const short8*)(hb + (size_t)(s & 0xFFFF)*DD + d0);
    short8 cv = *(const short8*)(combo + (size_t)(((unsigned)s) >> 16)*DD + d0);
    #pragma unroll
    for (int u = 0; u < 8; u++)
      acc[u] += fmaxf(b2f((unsigned short)hv[u]) + b2f((unsigned short)cv[u]), 0.f);
  }
  #pragma unroll
  for (int u = 0; u < 8; u++) acc[u] += __shfl_xor(acc[u], 32, 64);
  if (half == 0){
    short8 hn = *(const short8*)(hb + (size_t)n*DD + d0);
    short8 o;
    #pragma unroll
    for (int u = 0; u < 8; u++) o[u] = (short)f2b(b2f((unsigned short)hn[u]) + acc[u]);
    *(short8*)(t1 + (size_t)n*DD + d0) = o;
  }
}

// ---------------- MFMA GEMM: 128x256 tile, 8 waves, BK=32 ------------------
// PRO 0: 3-buffer pipeline, counted vmcnt, raw barriers (loads span steps)
// PRO 1: A = relu(bn(A))      (reg-staged, 2-buffer __syncthreads path)
// PRO 2: A = bn(A)+bn(A2)     (reg-staged, 2-buffer __syncthreads path)
template<int PRO, bool RELU, bool RES, bool STATS>
__global__ __launch_bounds__(512, 4) void mgemm_k(
    const unsigned short* __restrict__ A,
    const unsigned short* __restrict__ A2,
    const unsigned short* __restrict__ Bt,
    const float* __restrict__ bias,
    const unsigned short* __restrict__ res,
    const float* __restrict__ stIn1, const float* __restrict__ gg1, const float* __restrict__ bb1,
    const float* __restrict__ stIn2, const float* __restrict__ gg2, const float* __restrict__ bb2,
    float* __restrict__ statsOut,
    unsigned short* __restrict__ C,
    int Nn, int K)
{
  __shared__ __align__(16) __bf16 SA[3][128*32];     // 24 KB
  __shared__ __align__(16) __bf16 SB[3][256*32];     // 48 KB
  __shared__ __align__(16) float scF1[256], shF1[256], scF2[256], shF2[256];

  const int tid  = threadIdx.x;
  const int wid  = tid >> 6, lane = tid & 63;
  const int row0 = blockIdx.x * 128, col0 = blockIdx.y * 256;
  const int wrr = wid >> 2, wcc = wid & 3;           // wave tile: 64 rows x 64 cols
  const int fr = lane & 15, fq = lane >> 4;
  const int srow = tid >> 2, sch = tid & 3;          // staging: row, chunk
  const int swc = sch ^ (srow & 3);                  // pre-swizzled source chunk
  const int nt = K >> 5;

  if (PRO >= 1 && tid < 256){
    float mu = stIn1[tid]*(1.f/NN);
    float var = stIn1[256+tid]*(1.f/NN) - mu*mu;
    float s = rsqrtf(var + 1e-5f) * gg1[tid];
    scF1[tid] = s; shF1[tid] = bb1[tid] - mu*s;
    if (PRO == 2){
      float mu2 = stIn2[tid]*(1.f/NN);
      float va2 = stIn2[256+tid]*(1.f/NN) - mu2*mu2;
      float s2 = rsqrtf(va2 + 1e-5f) * gg2[tid];
      scF2[tid] = s2; shF2[tid] = bb2[tid] - mu2*s2;
    }
  }

  f32x4 acc[4][4];
  #pragma unroll
  for (int i = 0; i < 4; i++)
    #pragma unroll
    for (int j = 0; j < 4; j++) acc[i][j] = f32x4{0.f,0.f,0.f,0.f};

  auto stageA = [&](int buf, int kt){
    gld16(&SA[buf][(wid*16)*32],
          A + (size_t)(row0 + srow)*K + kt + swc*8);
  };
  auto stageB = [&](int buf, int kt){
    #pragma unroll
    for (int rr = 0; rr < 2; rr++)
      gld16(&SB[buf][(wid*16 + rr*128)*32],
            Bt + (size_t)(col0 + srow + rr*128)*K + kt + swc*8);
  };

  auto compute = [&](int buf){
    int kc = (fq ^ (fr & 3)) * 8;
    bf16x8 a[4], b[4];
    #pragma unroll
    for (int i = 0; i < 4; i++)
      a[i] = *(const bf16x8*)&SA[buf][(wrr*64 + 16*i + fr)*32 + kc];
    #pragma unroll
    for (int j = 0; j < 4; j++)
      b[j] = *(const bf16x8*)&SB[buf][(wcc*64 + 16*j + fr)*32 + kc];
    #pragma unroll
    for (int i = 0; i < 4; i++)
      #pragma unroll
      for (int j = 0; j < 4; j++)
        acc[i][j] = __builtin_amdgcn_mfma_f32_16x16x32_bf16(a[i], b[j], acc[i][j], 0, 0, 0);
  };

  if constexpr (PRO == 0){
    // 3-buffer pipeline: loads for step t+1 stay in flight across barrier t.
    stageA(0, 0);       stageB(0, 0);
    stageA(1, 32);      stageB(1, 32);
    for (int t = 0; t < nt; t++){
      if (t + 1 < nt) asm volatile("s_waitcnt vmcnt(3)" ::: "memory");
      else            asm volatile("s_waitcnt vmcnt(0)" ::: "memory");
      __builtin_amdgcn_s_barrier();
      __builtin_amdgcn_sched_barrier(0);
      if (t + 2 < nt){ stageA((t+2)%3, (t+2)*32); stageB((t+2)%3, (t+2)*32); }
      compute(t % 3);
    }
  } else {
    short8 g1v, g4v;
    auto loadA = [&](int kt){
      g1v = *(const short8*)(A + (size_t)(row0 + srow)*K + kt + sch*8);
      if (PRO == 2) g4v = *(const short8*)(A2 + (size_t)(row0 + srow)*K + kt + sch*8);
    };
    auto dswA = [&](int buf, int kt){
      f32x4 s1a = *(const f32x4*)&scF1[kt + sch*8];
      f32x4 s1b = *(const f32x4*)&scF1[kt + sch*8 + 4];
      f32x4 h1a = *(const f32x4*)&shF1[kt + sch*8];
      f32x4 h1b = *(const f32x4*)&shF1[kt + sch*8 + 4];
      f32x4 s2a, s2b, h2a, h2b;
      if (PRO == 2){
        s2a = *(const f32x4*)&scF2[kt + sch*8];
        s2b = *(const f32x4*)&scF2[kt + sch*8 + 4];
        h2a = *(const f32x4*)&shF2[kt + sch*8];
        h2b = *(const f32x4*)&shF2[kt + sch*8 + 4];
      }
      short8 o;
      #pragma unroll
      for (int u = 0; u < 8; u++){
        float sc = (u < 4) ? s1a[u&3] : s1b[u&3];
        float sh = (u < 4) ? h1a[u&3] : h1b[u&3];
        float v = b2f((unsigned short)g1v[u]) * sc + sh;
        if (PRO == 1) v = fmaxf(v, 0.f);
        if (PRO == 2){
          float sc2 = (u < 4) ? s2a[u&3] : s2b[u&3];
          float sh2 = (u < 4) ? h2a[u&3] : h2b[u&3];
          v += b2f((unsigned short)g4v[u]) * sc2 + sh2;
        }
        o[u] = (short)f2b(v);
      }
      *(short8*)&SA[buf][srow*32 + swc*8] = o;
    };
    loadA(0); stageB(0, 0);
    __syncthreads();                 // scF/shF visible before first dswA
    int cur = 0;
    for (int t = 0; t < nt; t++){
      dswA(cur, t*32);
      __syncthreads();
      if (t+1 < nt){ loadA((t+1)*32); stageB(cur^1, (t+1)*32); }
      compute(cur);
      cur ^= 1;
    }
  }

  // epilogue
  float bj[4];
  #pragma unroll
  for (int j = 0; j < 4; j++) bj[j] = bias[col0 + wcc*64 + 16*j + fr];

  #pragma unroll
  for (int i = 0; i < 4; i++){
    #pragma unroll
    for (int j = 0; j < 4; j++){
      int col = col0 + wcc*64 + 16*j + fr;
      #pragma unroll
      for (int r = 0; r < 4; r++){
        int row = row0 + wrr*64 + 16*i + fq*4 + r;
        float y = acc[i][j][r] + bj[j];
        if constexpr (RELU) y = fmaxf(y, 0.f);
        if constexpr (RES)  y += b2f(res[(size_t)row*256 + col]);
        acc[i][j][r] = y;
        C[(size_t)row*Nn + col] = f2b(y);
      }
    }
  }

  if constexpr (STATS){
    float* csA = (float*)&SA[0][0];          // SA dead; reuse as stats scratch
    float* cqA = csA + 256;
    __syncthreads();
    if (tid < 256){ csA[tid] = 0.f; cqA[tid] = 0.f; }
    __syncthreads();
    #pragma unroll
    for (int j = 0; j < 4; j++){
      float ps = 0.f, pq = 0.f;
      #pragma unroll
      for (int i = 0; i < 4; i++)
        #pragma unroll
        for (int r = 0; r < 4; r++){ float v = acc[i][j][r]; ps += v; pq += v*v; }
      ps += __shfl_xor(ps, 16, 64); pq += __shfl_xor(pq, 16, 64);
      ps += __shfl_xor(ps, 32, 64); pq += __shfl_xor(pq, 32, 64);
      if (lane < 16){
        atomicAdd(&csA[wcc*64 + 16*j + fr], ps);
        atomicAdd(&cqA[wcc*64 + 16*j + fr], pq);
      }
    }
    __syncthreads();
    if (tid < 256){
      atomicAdd(&statsOut[col0 + tid],       csA[tid]);
      atomicAdd(&statsOut[256 + col0 + tid], cqA[tid]);
    }
  }
}

// in-place BN apply (post-mlp2)
__global__ __launch_bounds__(256) void bnf_k(unsigned short* __restrict__ t,
                                             const float* __restrict__ st,
                                             const float* __restrict__ g,
                                             const float* __restrict__ b){
  __shared__ float sc[256], sh[256];
  int tid = threadIdx.x;
  {
    float mu  = st[tid] * (1.f/NN);
    float var = st[256+tid] * (1.f/NN) - mu*mu;
    float s   = rsqrtf(var + 1e-5f) * g[tid];
    sc[tid] = s; sh[tid] = b[tid] - mu*s;
  }
  __syncthreads();
  size_t base = ((size_t)blockIdx.x*256 + tid)*8;
  int c0 = (int)(base & 255);
  short8 v = *(const short8*)(t + base);
  short8 o;
  #pragma unroll
  for (int u = 0; u < 8; u++){
    float f = b2f((unsigned short)v[u])*sc[c0+u] + sh[c0+u];
    o[u] = (short)f2b(f);
  }
  *(short8*)(t + base) = o;
}

// ---------------- MFMA attention: 4 heads/block, barrier-free ---------------
__global__ __launch_bounds__(256) void attn_k(const unsigned short* __restrict__ qkv,
                                              unsigned short* __restrict__ o_out){
  int g   = blockIdx.x >> 1;
  int wid = threadIdx.x >> 6;
  int hh  = (blockIdx.x & 1)*4 + wid;
  int lane = threadIdx.x & 63;
  int fr = lane & 15, fq = lane >> 4;
  __shared__ __align__(16) unsigned short Vt[4][32*136];
  __shared__ __align__(16) unsigned short P[4][16*128];

  const unsigned short* qb = qkv + (size_t)g*128*768 + hh*32;
  const unsigned short* kb = qb + 256;
  const unsigned short* vb = qb + 512;

  #pragma unroll
  for (int h2 = 0; h2 < 2; h2++){
    int n = lane + 64*h2;
    const short8* vr = (const short8*)(vb + (size_t)n*768);
    #pragma unroll
    for (int c = 0; c < 4; c++){
      short8 v = vr[c];
      #pragma unroll
      for (int u = 0; u < 8; u++)
        Vt[wid][(c*8+u)*136 + n] = (unsigned short)v[u];
    }
  }
  bf16x8 bk[8];
  #pragma unroll
  for (int j = 0; j < 8; j++)
    bk[j] = *(const bf16x8*)(kb + (size_t)(16*j + fr)*768 + fq*8);
  // V^T fragments (intra-wave LDS dep; compiler inserts lgkmcnt)
  bf16x8 bv[4][2];
  #pragma unroll
  for (int kk = 0; kk < 4; kk++)
    #pragma unroll
    for (int j2 = 0; j2 < 2; j2++)
      bv[kk][j2] = *(const bf16x8*)&Vt[wid][(16*j2 + fr)*136 + kk*32 + fq*8];

  const float SCALE = 0.17677669529663687f;
  for (int m0 = 0; m0 < 128; m0 += 16){
    bf16x8 aq = *(const bf16x8*)(qb + (size_t)(m0 + fr)*768 + fq*8);
    f32x4 s[8];
    #pragma unroll
    for (int j = 0; j < 8; j++)
      s[j] = __builtin_amdgcn_mfma_f32_16x16x32_bf16(aq, bk[j], f32x4{0.f,0.f,0.f,0.f}, 0, 0, 0);
    float linv[4];
    #pragma unroll
    for (int r = 0; r < 4; r++){
      float mx = s[0][r];
      #pragma unroll
      for (int j = 1; j < 8; j++) mx = fmaxf(mx, s[j][r]);
      mx = fmaxf(mx, __shfl_xor(mx, 1, 64));
      mx = fmaxf(mx, __shfl_xor(mx, 2, 64));
      mx = fmaxf(mx, __shfl_xor(mx, 4, 64));
      mx = fmaxf(mx, __shfl_xor(mx, 8, 64));
      float sum = 0.f;
      #pragma unroll
      for (int j = 0; j < 8; j++){
        float p = __expf((s[j][r] - mx) * SCALE);
        unsigned short pb = f2b(p);
        s[j][r] = b2f(pb);
        sum += s[j][r];
      }
      sum += __shfl_xor(sum, 1, 64);
      sum += __shfl_xor(sum, 2, 64);
      sum += __shfl_xor(sum, 4, 64);
      sum += __shfl_xor(sum, 8, 64);
      linv[r] = 1.f / sum;
    }
    #pragma unroll
    for (int j = 0; j < 8; j++)
      #pragma unroll
      for (int r = 0; r < 4; r++){
        int row = fq*4 + r;
        int col = (16*j + fr) ^ ((row & 7) << 3);
        P[wid][row*128 + col] = f2b(s[j][r]);
      }
    f32x4 o0 = {0.f,0.f,0.f,0.f}, o1 = {0.f,0.f,0.f,0.f};
    #pragma unroll
    for (int kk = 0; kk < 4; kk++){
      bf16x8 pa = *(const bf16x8*)&P[wid][fr*128 + ((kk*32 + fq*8) ^ ((fr & 7) << 3))];
      o0 = __builtin_amdgcn_mfma_f32_16x16x32_bf16(pa, bv[kk][0], o0, 0, 0, 0);
      o1 = __builtin_amdgcn_mfma_f32_16x16x32_bf16(pa, bv[kk][1], o1, 0, 0, 0);
    }
    #pragma unroll
    for (int r = 0; r < 4; r++){
      int row = g*128 + m0 + fq*4 + r;
      unsigned short* dst = o_out + (size_t)row*DD + hh*32;
      dst[fr]      = f2b(o0[r]*linv[r]);
      dst[16 + fr] = f2b(o1[r]*linv[r]);
    }
  }
}

__global__ __launch_bounds__(256) void pool_k(const unsigned short* __restrict__ hb,
                                              float* __restrict__ out){
  int g = blockIdx.x, d = threadIdx.x;
  float acc = 0.f;
  for (int r = 0; r < NPGx; r++) acc += b2f(hb[(size_t)(g*NPGx + r)*DD + d]);
  out[g*DD + d] = acc;
}

// ---------------------------------------------------------------------------

extern "C" void kernel_launch(void* const* d_in, const int* in_sizes, int n_in,
                              void* d_out, int out_size, void* d_ws, size_t ws_size,
                              hipStream_t stream)
{
  const int*   x         = (const int*)  d_in[0];
  const int*   ei        = (const int*)  d_in[1];
  const int*   ea        = (const int*)  d_in[2];
  const float* pe        = (const float*)d_in[4];
  const float* atom_emb  = (const float*)d_in[5];
  const float* bond_emb  = (const float*)d_in[6];
  const float* pe_w      = (const float*)d_in[7];
  const float* pe_b      = (const float*)d_in[8];
  const float* gine_w1   = (const float*)d_in[9];
  const float* gine_b1   = (const float*)d_in[10];
  const float* gine_g1   = (const float*)d_in[11];
  const float* gine_be1  = (const float*)d_in[12];
  const float* gine_w2   = (const float*)d_in[13];
  const float* gine_b2   = (const float*)d_in[14];
  const float* attn_wqkv = (const float*)d_in[15];
  const float* attn_bqkv = (const float*)d_in[16];
  const float* attn_wo   = (const float*)d_in[17];
  const float* attn_bo   = (const float*)d_in[18];
  const float* n1_g      = (const float*)d_in[19];
  const float* n1_b      = (const float*)d_in[20];
  const float* n2_g      = (const float*)d_in[21];
  const float* n2_b      = (const float*)d_in[22];
  const float* n3_g      = (const float*)d_in[23];
  const float* n3_b      = (const float*)d_in[24];
  const float* mlp_w1    = (const float*)d_in[25];
  const float* mlp_b1    = (const float*)d_in[26];
  const float* mlp_w2    = (const float*)d_in[27];
  const float* mlp_b2    = (const float*)d_in[28];
  float* out = (float*)d_out;

  char* wsp = (char*)d_ws;
  size_t off = 0;
  auto alloc = [&](size_t bytes)->void*{
    void* p = wsp + off; off += (bytes + 255) & ~(size_t)255; return p;
  };
  unsigned short* hb  = (unsigned short*)alloc((size_t)NN*DD*2);
  unsigned short* t1  = (unsigned short*)alloc((size_t)NN*DD*2);
  unsigned short* t2  = (unsigned short*)alloc((size_t)NN*DD*2);
  unsigned short* t4  = (unsigned short*)alloc((size_t)NN*DD*2);
  unsigned short* big = (unsigned short*)alloc((size_t)NN*768*2);
  unsigned short* wt  = (unsigned short*)alloc((size_t)LL*655360*2);
  unsigned short* combo = (unsigned short*)alloc((size_t)512*DD*2);
  int*   row_ptr = (int*)  alloc((size_t)(NN+1)*4);
  int*   cursor  = (int*)  alloc((size_t)NN*4);
  int*   slot    = (int*)  alloc((size_t)EE*4);
  float* stats   = (float*)alloc((size_t)LL*4*2*DD*4);
  if (off > ws_size) return;

  hipMemsetAsync(stats,  0, (size_t)LL*4*2*DD*4, stream);
  hipMemsetAsync(cursor, 0, (size_t)NN*4, stream);
  combo_k<<<512, 256, 0, stream>>>(bond_emb, combo);
  twt_k  <<<LL*160, 256, 0, stream>>>(gine_w1, gine_w2, attn_wqkv, attn_wo,
                                      mlp_w1, mlp_w2, wt);
  hist_k <<<512, 256, 0, stream>>>(ei, cursor);
  scan_k <<<1, 1024, 0, stream>>>(cursor, row_ptr);
  fill_k <<<512, 256, 0, stream>>>(ei, ea, cursor, slot);
  enc_k  <<<2048, 256, 0, stream>>>(x, pe, atom_emb, pe_w, pe_b, hb);

  for (int l = 0; l < LL; l++){
    unsigned short* wl = wt + (size_t)l*655360;
    const float* b1   = gine_b1   + l*DD;
    const float* b2   = gine_b2   + l*DD;
    const float* bqkv = attn_bqkv + l*768;
    const float* bo   = attn_bo   + l*DD;
    const float* mb1  = mlp_b1    + l*FFF;
    const float* mb2  = mlp_b2    + l*DD;
    float* S0 = stats + (l*4+0)*2*DD;
    float* S1 = stats + (l*4+1)*2*DD;
    float* S2 = stats + (l*4+2)*2*DD;
    float* S3 = stats + (l*4+3)*2*DD;

    gather_k<<<NN/4, 256, 0, stream>>>(hb, row_ptr, slot, combo, t1);
    // t2 = t1 @ w1 + b1 ; stats S0
    mgemm_k<0,false,false,true><<<dim3(512,1), 512, 0, stream>>>(
        t1, nullptr, wl + 0, b1, nullptr,
        nullptr,nullptr,nullptr, nullptr,nullptr,nullptr, S0, t2, 256, 256);
    // t1 = relu( relu(bn(t2;S0,g1,be1)) @ w2 + b2 ) + hb ; stats S1
    mgemm_k<1,true,true,true><<<dim3(512,1), 512, 0, stream>>>(
        t2, nullptr, wl + 65536, b2, hb,
        S0, gine_g1 + l*DD, gine_be1 + l*DD, nullptr,nullptr,nullptr, S1, t1, 256, 256);
    // big = hb @ wqkv + bqkv
    mgemm_k<0,false,false,false><<<dim3(512,3), 512, 0, stream>>>(
        hb, nullptr, wl + 131072, bqkv, nullptr,
        nullptr,nullptr,nullptr, nullptr,nullptr,nullptr, nullptr, big, 768, 256);
    attn_k<<<GG*2, 256, 0, stream>>>(big, t2);
    // t4 = t2 @ wo + bo + hb ; stats S2
    mgemm_k<0,false,true,true><<<dim3(512,1), 512, 0, stream>>>(
        t2, nullptr, wl + 327680, bo, hb,
        nullptr,nullptr,nullptr, nullptr,nullptr,nullptr, S2, t4, 256, 256);
    // big = relu( (bn(t1;S1,n1)+bn(t4;S2,n2)) @ mw1 + mb1 )
    mgemm_k<2,true,false,false><<<dim3(512,2), 512, 0, stream>>>(
        t1, t4, wl + 393216, mb1, nullptr,
        S1, n1_g + l*DD, n1_b + l*DD, S2, n2_g + l*DD, n2_b + l*DD, nullptr, big, 512, 256);
    // hb = big @ mw2 + mb2 ; stats S3
    mgemm_k<0,false,false,true><<<dim3(512,1), 512, 0, stream>>>(
        big, nullptr, wl + 524288, mb2, nullptr,
        nullptr,nullptr,nullptr, nullptr,nullptr,nullptr, S3, hb, 256, 512);
    bnf_k<<<NN*DD/2048, 256, 0, stream>>>(hb, S3, n3_g + l*DD, n3_b + l*DD);
  }
  pool_k<<<GG, 256, 0, stream>>>(hb, out);
}

// Round 8
// 1527.287 us; speedup vs baseline: 4.5694x; 1.0300x over previous
//
#include <hip/hip_runtime.h>
#include <stdint.h>

// ---------------------------------------------------------------------------
// GPS (GINE + dense MHA + MLP, BatchNorm) forward, MI355X round-8.
// attn: no max-subtraction (shift-invariant, scores bounded), row-sum via
// MFMA ones-column (kills all softmax shuffles). mgemm: setprio around MFMA.
// ---------------------------------------------------------------------------

#define NN   65536
#define EE   524288
#define DD   256
#define LL   4
#define GG   512
#define NPGx 128
#define FFF  512

typedef __attribute__((ext_vector_type(8))) short short8;
typedef __attribute__((ext_vector_type(8))) __bf16 bf16x8;
typedef __attribute__((ext_vector_type(4))) float f32x4;

__device__ __forceinline__ float b2f(unsigned short u){
  union {unsigned int i; float f;} z; z.i = ((unsigned int)u) << 16; return z.f;
}
__device__ __forceinline__ unsigned short f2b(float f){
  union {float f; unsigned int i;} z; z.f = f;
  unsigned int r = z.i + 0x7fff + ((z.i >> 16) & 1u);
  return (unsigned short)(r >> 16);
}

__device__ __forceinline__ void gld16(void* lds, const void* g){
  __builtin_amdgcn_global_load_lds(
      (const __attribute__((address_space(1))) void*)g,
      (__attribute__((address_space(3))) void*)lds, 16, 0, 0);
}

// ---------------- preprocessing ----------------

__global__ __launch_bounds__(256) void combo_k(const float* __restrict__ be,
                                               unsigned short* __restrict__ tab){
  int c = blockIdx.x, d = threadIdx.x;
  int a0 = c & 7, a1 = (c >> 3) & 7, a2 = (c >> 6) & 7;
  tab[c*DD + d] = f2b(be[a0*DD + d] + be[(8 + a1)*DD + d] + be[(16 + a2)*DD + d]);
}

__global__ __launch_bounds__(256) void hist_k(const int* __restrict__ ei,
                                              int* __restrict__ cnt){
  for (int i = blockIdx.x*256 + threadIdx.x; i < EE; i += gridDim.x*256)
    atomicAdd(&cnt[ei[EE + i]], 1);
}

__global__ __launch_bounds__(1024) void scan_k(int* __restrict__ cnt,
                                               int* __restrict__ row_ptr){
  __shared__ int sd[1024];
  __shared__ int carry;
  int t = threadIdx.x;
  if (t == 0) carry = 0;
  __syncthreads();
  for (int base = 0; base < NN; base += 4096){
    int idx = base + t*4;
    int v0 = cnt[idx+0], v1 = cnt[idx+1], v2 = cnt[idx+2], v3 = cnt[idx+3];
    int s = v0 + v1 + v2 + v3;
    sd[t] = s; __syncthreads();
    for (int offd = 1; offd < 1024; offd <<= 1){
      int xv = (t >= offd) ? sd[t - offd] : 0;
      __syncthreads();
      sd[t] += xv;
      __syncthreads();
    }
    int excl = sd[t] - s + carry;
    row_ptr[idx+0] = excl;             cnt[idx+0] = excl;
    row_ptr[idx+1] = excl + v0;        cnt[idx+1] = excl + v0;
    row_ptr[idx+2] = excl + v0 + v1;   cnt[idx+2] = excl + v0 + v1;
    row_ptr[idx+3] = excl + v0+v1+v2;  cnt[idx+3] = excl + v0+v1+v2;
    __syncthreads();
    if (t == 0) carry += sd[1023];
    __syncthreads();
  }
  if (t == 0) row_ptr[NN] = carry;
}

__global__ __launch_bounds__(256) void fill_k(const int* __restrict__ ei,
                                              const int* __restrict__ ea,
                                              int* __restrict__ cursor,
                                              int* __restrict__ slot){
  for (int i = blockIdx.x*256 + threadIdx.x; i < EE; i += gridDim.x*256){
    int s  = ei[i];
    int dn = ei[EE + i];
    int a0 = ea[i*3+0], a1 = ea[i*3+1], a2 = ea[i*3+2];
    int cb = a0 | (a1 << 3) | (a2 << 6);
    int p = atomicAdd(&cursor[dn], 1);
    slot[p] = s | (cb << 16);
  }
}

// tiled weight transpose + bf16: 64x64 tiles via LDS
__global__ __launch_bounds__(256) void twt_k(const float* __restrict__ w1,
                                             const float* __restrict__ w2,
                                             const float* __restrict__ wqkv,
                                             const float* __restrict__ wo,
                                             const float* __restrict__ m1,
                                             const float* __restrict__ m2,
                                             unsigned short* __restrict__ wt){
  __shared__ float tile[64][65];
  int l = blockIdx.x / 160;
  int r = blockIdx.x % 160;
  const float* src; unsigned short* dst; int K, Nsrc, t0;
  unsigned short* wl = wt + (size_t)l*655360;
  if (r < 16)      { src = w1  +(size_t)l*65536;  dst = wl;        K=256; Nsrc=256; t0=r; }
  else if (r < 32) { src = w2  +(size_t)l*65536;  dst = wl+65536;  K=256; Nsrc=256; t0=r-16; }
  else if (r < 80) { src = wqkv+(size_t)l*196608; dst = wl+131072; K=256; Nsrc=768; t0=r-32; }
  else if (r < 96) { src = wo  +(size_t)l*65536;  dst = wl+327680; K=256; Nsrc=256; t0=r-80; }
  else if (r < 128){ src = m1  +(size_t)l*131072; dst = wl+393216; K=256; Nsrc=512; t0=r-96; }
  else             { src = m2  +(size_t)l*131072; dst = wl+524288; K=512; Nsrc=256; t0=r-128; }
  int nkt = K >> 6;
  int tn = t0 / nkt, tk = t0 % nkt;
  int rr = threadIdx.x >> 6, cc = threadIdx.x & 63;
  for (int p = 0; p < 64; p += 4)
    tile[p+rr][cc] = src[(size_t)(tk*64 + p + rr)*Nsrc + tn*64 + cc];
  __syncthreads();
  for (int p = 0; p < 64; p += 4)
    dst[(size_t)(tn*64 + p + rr)*K + tk*64 + cc] = f2b(tile[cc][p+rr]);
}

// AtomEncoder + PE: wave owns d-slice, 8 nodes/wave, pe_w in registers
__global__ __launch_bounds__(256) void enc_k(const int* __restrict__ x,
                                             const float* __restrict__ pe,
                                             const float* __restrict__ atom_emb,
                                             const float* __restrict__ pe_w,
                                             const float* __restrict__ pe_b,
                                             unsigned short* __restrict__ hb){
  int wv = blockIdx.x*4 + (threadIdx.x >> 6);
  int lane = threadIdx.x & 63;
  int d0 = lane*4;
  f32x4 pw[20];
  #pragma unroll
  for (int t = 0; t < 20; t++) pw[t] = *(const f32x4*)(pe_w + t*DD + d0);
  f32x4 pb = *(const f32x4*)(pe_b + d0);
  int n0 = wv*8;
  for (int n = n0; n < n0 + 8; n++){
    f32x4 acc = pb;
    #pragma unroll
    for (int i = 0; i < 9; i++){
      int xi = x[n*9 + i];
      acc += *(const f32x4*)(atom_emb + (size_t)(i*128 + xi)*DD + d0);
    }
    #pragma unroll
    for (int t = 0; t < 20; t++) acc += pe[n*20 + t] * pw[t];
    ushort4 o;
    o.x = f2b(acc[0]); o.y = f2b(acc[1]); o.z = f2b(acc[2]); o.w = f2b(acc[3]);
    *(ushort4*)(hb + (size_t)n*DD + d0) = o;
  }
}

// GINE gather: wave per node, 2 edges/iter, unrolled 2x
__global__ __launch_bounds__(256) void gather_k(const unsigned short* __restrict__ hb,
                                                const int* __restrict__ row_ptr,
                                                const int* __restrict__ slot,
                                                const unsigned short* __restrict__ combo,
                                                unsigned short* __restrict__ t1){
  int w = threadIdx.x >> 6, lane = threadIdx.x & 63;
  int n = blockIdx.x*4 + w;
  int half = lane >> 5, l32 = lane & 31;
  int d0 = l32*8;
  int beg = row_ptr[n], end = row_ptr[n+1];
  float acc[8];
  #pragma unroll
  for (int u = 0; u < 8; u++) acc[u] = 0.f;
  int e = beg + half;
  for (; e + 2 < end; e += 4){
    int sA = slot[e], sB = slot[e+2];
    short8 hvA = *(const short8*)(hb + (size_t)(sA & 0xFFFF)*DD + d0);
    short8 cvA = *(const short8*)(combo + (size_t)(((unsigned)sA) >> 16)*DD + d0);
    short8 hvB = *(const short8*)(hb + (size_t)(sB & 0xFFFF)*DD + d0);
    short8 cvB = *(const short8*)(combo + (size_t)(((unsigned)sB) >> 16)*DD + d0);
    #pragma unroll
    for (int u = 0; u < 8; u++)
      acc[u] += fmaxf(b2f((unsigned short)hvA[u]) + b2f((unsigned short)cvA[u]), 0.f);
    #pragma unroll
    for (int u = 0; u < 8; u++)
      acc[u] += fmaxf(b2f((unsigned short)hvB[u]) + b2f((unsigned short)cvB[u]), 0.f);
  }
  for (; e < end; e += 2){
    int s = slot[e];
    short8 hv = *(const short8*)(hb + (size_t)(s & 0xFFFF)*DD + d0);
    short8 cv = *(const short8*)(combo + (size_t)(((unsigned)s) >> 16)*DD + d0);
    #pragma unroll
    for (int u = 0; u < 8; u++)
      acc[u] += fmaxf(b2f((unsigned short)hv[u]) + b2f((unsigned short)cv[u]), 0.f);
  }
  #pragma unroll
  for (int u = 0; u < 8; u++) acc[u] += __shfl_xor(acc[u], 32, 64);
  if (half == 0){
    short8 hn = *(const short8*)(hb + (size_t)n*DD + d0);
    short8 o;
    #pragma unroll
    for (int u = 0; u < 8; u++) o[u] = (short)f2b(b2f((unsigned short)hn[u]) + acc[u]);
    *(short8*)(t1 + (size_t)n*DD + d0) = o;
  }
}

// ---------------- MFMA GEMM: 128x256 tile, 8 waves, BK=32 ------------------
// PRO 0: 3-buffer pipeline, counted vmcnt, raw barriers (loads span steps)
// PRO 1: A = relu(bn(A))      (reg-staged, 2-buffer __syncthreads path)
// PRO 2: A = bn(A)+bn(A2)     (reg-staged, 2-buffer __syncthreads path)
template<int PRO, bool RELU, bool RES, bool STATS>
__global__ __launch_bounds__(512, 4) void mgemm_k(
    const unsigned short* __restrict__ A,
    const unsigned short* __restrict__ A2,
    const unsigned short* __restrict__ Bt,
    const float* __restrict__ bias,
    const unsigned short* __restrict__ res,
    const float* __restrict__ stIn1, const float* __restrict__ gg1, const float* __restrict__ bb1,
    const float* __restrict__ stIn2, const float* __restrict__ gg2, const float* __restrict__ bb2,
    float* __restrict__ statsOut,
    unsigned short* __restrict__ C,
    int Nn, int K)
{
  __shared__ __align__(16) __bf16 SA[3][128*32];     // 24 KB
  __shared__ __align__(16) __bf16 SB[3][256*32];     // 48 KB
  __shared__ __align__(16) float scF1[256], shF1[256], scF2[256], shF2[256];

  const int tid  = threadIdx.x;
  const int wid  = tid >> 6, lane = tid & 63;
  const int row0 = blockIdx.x * 128, col0 = blockIdx.y * 256;
  const int wrr = wid >> 2, wcc = wid & 3;           // wave tile: 64 rows x 64 cols
  const int fr = lane & 15, fq = lane >> 4;
  const int srow = tid >> 2, sch = tid & 3;          // staging: row, chunk
  const int swc = sch ^ (srow & 3);                  // pre-swizzled source chunk
  const int nt = K >> 5;

  if (PRO >= 1 && tid < 256){
    float mu = stIn1[tid]*(1.f/NN);
    float var = stIn1[256+tid]*(1.f/NN) - mu*mu;
    float s = rsqrtf(var + 1e-5f) * gg1[tid];
    scF1[tid] = s; shF1[tid] = bb1[tid] - mu*s;
    if (PRO == 2){
      float mu2 = stIn2[tid]*(1.f/NN);
      float va2 = stIn2[256+tid]*(1.f/NN) - mu2*mu2;
      float s2 = rsqrtf(va2 + 1e-5f) * gg2[tid];
      scF2[tid] = s2; shF2[tid] = bb2[tid] - mu2*s2;
    }
  }

  f32x4 acc[4][4];
  #pragma unroll
  for (int i = 0; i < 4; i++)
    #pragma unroll
    for (int j = 0; j < 4; j++) acc[i][j] = f32x4{0.f,0.f,0.f,0.f};

  auto stageA = [&](int buf, int kt){
    gld16(&SA[buf][(wid*16)*32],
          A + (size_t)(row0 + srow)*K + kt + swc*8);
  };
  auto stageB = [&](int buf, int kt){
    #pragma unroll
    for (int rr = 0; rr < 2; rr++)
      gld16(&SB[buf][(wid*16 + rr*128)*32],
            Bt + (size_t)(col0 + srow + rr*128)*K + kt + swc*8);
  };

  auto compute = [&](int buf){
    int kc = (fq ^ (fr & 3)) * 8;
    bf16x8 a[4], b[4];
    #pragma unroll
    for (int i = 0; i < 4; i++)
      a[i] = *(const bf16x8*)&SA[buf][(wrr*64 + 16*i + fr)*32 + kc];
    #pragma unroll
    for (int j = 0; j < 4; j++)
      b[j] = *(const bf16x8*)&SB[buf][(wcc*64 + 16*j + fr)*32 + kc];
    __builtin_amdgcn_s_setprio(1);
    #pragma unroll
    for (int i = 0; i < 4; i++)
      #pragma unroll
      for (int j = 0; j < 4; j++)
        acc[i][j] = __builtin_amdgcn_mfma_f32_16x16x32_bf16(a[i], b[j], acc[i][j], 0, 0, 0);
    __builtin_amdgcn_s_setprio(0);
  };

  if constexpr (PRO == 0){
    // 3-buffer pipeline: loads for step t+1 stay in flight across barrier t.
    stageA(0, 0);       stageB(0, 0);
    stageA(1, 32);      stageB(1, 32);
    for (int t = 0; t < nt; t++){
      if (t + 1 < nt) asm volatile("s_waitcnt vmcnt(3)" ::: "memory");
      else            asm volatile("s_waitcnt vmcnt(0)" ::: "memory");
      __builtin_amdgcn_s_barrier();
      __builtin_amdgcn_sched_barrier(0);
      if (t + 2 < nt){ stageA((t+2)%3, (t+2)*32); stageB((t+2)%3, (t+2)*32); }
      compute(t % 3);
    }
  } else {
    short8 g1v, g4v;
    auto loadA = [&](int kt){
      g1v = *(const short8*)(A + (size_t)(row0 + srow)*K + kt + sch*8);
      if (PRO == 2) g4v = *(const short8*)(A2 + (size_t)(row0 + srow)*K + kt + sch*8);
    };
    auto dswA = [&](int buf, int kt){
      f32x4 s1a = *(const f32x4*)&scF1[kt + sch*8];
      f32x4 s1b = *(const f32x4*)&scF1[kt + sch*8 + 4];
      f32x4 h1a = *(const f32x4*)&shF1[kt + sch*8];
      f32x4 h1b = *(const f32x4*)&shF1[kt + sch*8 + 4];
      f32x4 s2a, s2b, h2a, h2b;
      if (PRO == 2){
        s2a = *(const f32x4*)&scF2[kt + sch*8];
        s2b = *(const f32x4*)&scF2[kt + sch*8 + 4];
        h2a = *(const f32x4*)&shF2[kt + sch*8];
        h2b = *(const f32x4*)&shF2[kt + sch*8 + 4];
      }
      short8 o;
      #pragma unroll
      for (int u = 0; u < 8; u++){
        float sc = (u < 4) ? s1a[u&3] : s1b[u&3];
        float sh = (u < 4) ? h1a[u&3] : h1b[u&3];
        float v = b2f((unsigned short)g1v[u]) * sc + sh;
        if (PRO == 1) v = fmaxf(v, 0.f);
        if (PRO == 2){
          float sc2 = (u < 4) ? s2a[u&3] : s2b[u&3];
          float sh2 = (u < 4) ? h2a[u&3] : h2b[u&3];
          v += b2f((unsigned short)g4v[u]) * sc2 + sh2;
        }
        o[u] = (short)f2b(v);
      }
      *(short8*)&SA[buf][srow*32 + swc*8] = o;
    };
    loadA(0); stageB(0, 0);
    __syncthreads();                 // scF/shF visible before first dswA
    int cur = 0;
    for (int t = 0; t < nt; t++){
      dswA(cur, t*32);
      __syncthreads();
      if (t+1 < nt){ loadA((t+1)*32); stageB(cur^1, (t+1)*32); }
      compute(cur);
      cur ^= 1;
    }
  }

  // epilogue
  float bj[4];
  #pragma unroll
  for (int j = 0; j < 4; j++) bj[j] = bias[col0 + wcc*64 + 16*j + fr];

  #pragma unroll
  for (int i = 0; i < 4; i++){
    #pragma unroll
    for (int j = 0; j < 4; j++){
      int col = col0 + wcc*64 + 16*j + fr;
      #pragma unroll
      for (int r = 0; r < 4; r++){
        int row = row0 + wrr*64 + 16*i + fq*4 + r;
        float y = acc[i][j][r] + bj[j];
        if constexpr (RELU) y = fmaxf(y, 0.f);
        if constexpr (RES)  y += b2f(res[(size_t)row*256 + col]);
        acc[i][j][r] = y;
        C[(size_t)row*Nn + col] = f2b(y);
      }
    }
  }

  if constexpr (STATS){
    float* csA = (float*)&SA[0][0];          // SA dead; reuse as stats scratch
    float* cqA = csA + 256;
    __syncthreads();
    if (tid < 256){ csA[tid] = 0.f; cqA[tid] = 0.f; }
    __syncthreads();
    #pragma unroll
    for (int j = 0; j < 4; j++){
      float ps = 0.f, pq = 0.f;
      #pragma unroll
      for (int i = 0; i < 4; i++)
        #pragma unroll
        for (int r = 0; r < 4; r++){ float v = acc[i][j][r]; ps += v; pq += v*v; }
      ps += __shfl_xor(ps, 16, 64); pq += __shfl_xor(pq, 16, 64);
      ps += __shfl_xor(ps, 32, 64); pq += __shfl_xor(pq, 32, 64);
      if (lane < 16){
        atomicAdd(&csA[wcc*64 + 16*j + fr], ps);
        atomicAdd(&cqA[wcc*64 + 16*j + fr], pq);
      }
    }
    __syncthreads();
    if (tid < 256){
      atomicAdd(&statsOut[col0 + tid],       csA[tid]);
      atomicAdd(&statsOut[256 + col0 + tid], cqA[tid]);
    }
  }
}

// in-place BN apply (post-mlp2)
__global__ __launch_bounds__(256) void bnf_k(unsigned short* __restrict__ t,
                                             const float* __restrict__ st,
                                             const float* __restrict__ g,
                                             const float* __restrict__ b){
  __shared__ float sc[256], sh[256];
  int tid = threadIdx.x;
  {
    float mu  = st[tid] * (1.f/NN);
    float var = st[256+tid] * (1.f/NN) - mu*mu;
    float s   = rsqrtf(var + 1e-5f) * g[tid];
    sc[tid] = s; sh[tid] = b[tid] - mu*s;
  }
  __syncthreads();
  size_t base = ((size_t)blockIdx.x*256 + tid)*8;
  int c0 = (int)(base & 255);
  short8 v = *(const short8*)(t + base);
  short8 o;
  #pragma unroll
  for (int u = 0; u < 8; u++){
    float f = b2f((unsigned short)v[u])*sc[c0+u] + sh[c0+u];
    o[u] = (short)f2b(f);
  }
  *(short8*)(t + base) = o;
}

// ---------------- MFMA attention: 4 heads/block, barrier-free ---------------
// No max-subtraction (softmax shift-invariant; scores bounded ~|3|).
// Row-sum of bf16-rounded P via MFMA ones-column (col-replicated to all lanes).
__global__ __launch_bounds__(256) void attn_k(const unsigned short* __restrict__ qkv,
                                              unsigned short* __restrict__ o_out){
  int g   = blockIdx.x >> 1;
  int wid = threadIdx.x >> 6;
  int hh  = (blockIdx.x & 1)*4 + wid;
  int lane = threadIdx.x & 63;
  int fr = lane & 15, fq = lane >> 4;
  __shared__ __align__(16) unsigned short Vt[4][32*136];
  __shared__ __align__(16) unsigned short P[4][16*128];

  const unsigned short* qb = qkv + (size_t)g*128*768 + hh*32;
  const unsigned short* kb = qb + 256;
  const unsigned short* vb = qb + 512;

  #pragma unroll
  for (int h2 = 0; h2 < 2; h2++){
    int n = lane + 64*h2;
    const short8* vr = (const short8*)(vb + (size_t)n*768);
    #pragma unroll
    for (int c = 0; c < 4; c++){
      short8 v = vr[c];
      #pragma unroll
      for (int u = 0; u < 8; u++)
        Vt[wid][(c*8+u)*136 + n] = (unsigned short)v[u];
    }
  }
  bf16x8 bk[8];
  #pragma unroll
  for (int j = 0; j < 8; j++)
    bk[j] = *(const bf16x8*)(kb + (size_t)(16*j + fr)*768 + fq*8);
  // V^T fragments (intra-wave LDS dep; compiler inserts lgkmcnt)
  bf16x8 bv[4][2];
  #pragma unroll
  for (int kk = 0; kk < 4; kk++)
    #pragma unroll
    for (int j2 = 0; j2 < 2; j2++)
      bv[kk][j2] = *(const bf16x8*)&Vt[wid][(16*j2 + fr)*136 + kk*32 + fq*8];

  bf16x8 ones;
  #pragma unroll
  for (int u = 0; u < 8; u++) ones[u] = (__bf16)1.0f;

  const float SCALE = 0.17677669529663687f;   // 1/sqrt(32)
  for (int m0 = 0; m0 < 128; m0 += 16){
    bf16x8 aq = *(const bf16x8*)(qb + (size_t)(m0 + fr)*768 + fq*8);
    f32x4 s[8];
    #pragma unroll
    for (int j = 0; j < 8; j++)
      s[j] = __builtin_amdgcn_mfma_f32_16x16x32_bf16(aq, bk[j], f32x4{0.f,0.f,0.f,0.f}, 0, 0, 0);
    // P = exp(s*scale), bf16-rounded, written straight to swizzled LDS
    #pragma unroll
    for (int j = 0; j < 8; j++)
      #pragma unroll
      for (int r = 0; r < 4; r++){
        int row = fq*4 + r;
        int col = (16*j + fr) ^ ((row & 7) << 3);
        P[wid][row*128 + col] = f2b(__expf(s[j][r] * SCALE));
      }
    f32x4 o0 = {0.f,0.f,0.f,0.f}, o1 = {0.f,0.f,0.f,0.f};
    f32x4 os = {0.f,0.f,0.f,0.f};
    #pragma unroll
    for (int kk = 0; kk < 4; kk++){
      bf16x8 pa = *(const bf16x8*)&P[wid][fr*128 + ((kk*32 + fq*8) ^ ((fr & 7) << 3))];
      o0 = __builtin_amdgcn_mfma_f32_16x16x32_bf16(pa, bv[kk][0], o0, 0, 0, 0);
      o1 = __builtin_amdgcn_mfma_f32_16x16x32_bf16(pa, bv[kk][1], o1, 0, 0, 0);
      os = __builtin_amdgcn_mfma_f32_16x16x32_bf16(pa, ones,      os, 0, 0, 0);
    }
    #pragma unroll
    for (int r = 0; r < 4; r++){
      float linv = 1.f / os[r];
      int row = g*128 + m0 + fq*4 + r;
      unsigned short* dst = o_out + (size_t)row*DD + hh*32;
      dst[fr]      = f2b(o0[r]*linv);
      dst[16 + fr] = f2b(o1[r]*linv);
    }
  }
}

__global__ __launch_bounds__(256) void pool_k(const unsigned short* __restrict__ hb,
                                              float* __restrict__ out){
  int g = blockIdx.x, d = threadIdx.x;
  float acc = 0.f;
  for (int r = 0; r < NPGx; r++) acc += b2f(hb[(size_t)(g*NPGx + r)*DD + d]);
  out[g*DD + d] = acc;
}

// ---------------------------------------------------------------------------

extern "C" void kernel_launch(void* const* d_in, const int* in_sizes, int n_in,
                              void* d_out, int out_size, void* d_ws, size_t ws_size,
                              hipStream_t stream)
{
  const int*   x         = (const int*)  d_in[0];
  const int*   ei        = (const int*)  d_in[1];
  const int*   ea        = (const int*)  d_in[2];
  const float* pe        = (const float*)d_in[4];
  const float* atom_emb  = (const float*)d_in[5];
  const float* bond_emb  = (const float*)d_in[6];
  const float* pe_w      = (const float*)d_in[7];
  const float* pe_b      = (const float*)d_in[8];
  const float* gine_w1   = (const float*)d_in[9];
  const float* gine_b1   = (const float*)d_in[10];
  const float* gine_g1   = (const float*)d_in[11];
  const float* gine_be1  = (const float*)d_in[12];
  const float* gine_w2   = (const float*)d_in[13];
  const float* gine_b2   = (const float*)d_in[14];
  const float* attn_wqkv = (const float*)d_in[15];
  const float* attn_bqkv = (const float*)d_in[16];
  const float* attn_wo   = (const float*)d_in[17];
  const float* attn_bo   = (const float*)d_in[18];
  const float* n1_g      = (const float*)d_in[19];
  const float* n1_b      = (const float*)d_in[20];
  const float* n2_g      = (const float*)d_in[21];
  const float* n2_b      = (const float*)d_in[22];
  const float* n3_g      = (const float*)d_in[23];
  const float* n3_b      = (const float*)d_in[24];
  const float* mlp_w1    = (const float*)d_in[25];
  const float* mlp_b1    = (const float*)d_in[26];
  const float* mlp_w2    = (const float*)d_in[27];
  const float* mlp_b2    = (const float*)d_in[28];
  float* out = (float*)d_out;

  char* wsp = (char*)d_ws;
  size_t off = 0;
  auto alloc = [&](size_t bytes)->void*{
    void* p = wsp + off; off += (bytes + 255) & ~(size_t)255; return p;
  };
  unsigned short* hb  = (unsigned short*)alloc((size_t)NN*DD*2);
  unsigned short* t1  = (unsigned short*)alloc((size_t)NN*DD*2);
  unsigned short* t2  = (unsigned short*)alloc((size_t)NN*DD*2);
  unsigned short* t4  = (unsigned short*)alloc((size_t)NN*DD*2);
  unsigned short* big = (unsigned short*)alloc((size_t)NN*768*2);
  unsigned short* wt  = (unsigned short*)alloc((size_t)LL*655360*2);
  unsigned short* combo = (unsigned short*)alloc((size_t)512*DD*2);
  int*   row_ptr = (int*)  alloc((size_t)(NN+1)*4);
  int*   cursor  = (int*)  alloc((size_t)NN*4);
  int*   slot    = (int*)  alloc((size_t)EE*4);
  float* stats   = (float*)alloc((size_t)LL*4*2*DD*4);
  if (off > ws_size) return;

  hipMemsetAsync(stats,  0, (size_t)LL*4*2*DD*4, stream);
  hipMemsetAsync(cursor, 0, (size_t)NN*4, stream);
  combo_k<<<512, 256, 0, stream>>>(bond_emb, combo);
  twt_k  <<<LL*160, 256, 0, stream>>>(gine_w1, gine_w2, attn_wqkv, attn_wo,
                                      mlp_w1, mlp_w2, wt);
  hist_k <<<512, 256, 0, stream>>>(ei, cursor);
  scan_k <<<1, 1024, 0, stream>>>(cursor, row_ptr);
  fill_k <<<512, 256, 0, stream>>>(ei, ea, cursor, slot);
  enc_k  <<<2048, 256, 0, stream>>>(x, pe, atom_emb, pe_w, pe_b, hb);

  for (int l = 0; l < LL; l++){
    unsigned short* wl = wt + (size_t)l*655360;
    const float* b1   = gine_b1   + l*DD;
    const float* b2   = gine_b2   + l*DD;
    const float* bqkv = attn_bqkv + l*768;
    const float* bo   = attn_bo   + l*DD;
    const float* mb1  = mlp_b1    + l*FFF;
    const float* mb2  = mlp_b2    + l*DD;
    float* S0 = stats + (l*4+0)*2*DD;
    float* S1 = stats + (l*4+1)*2*DD;
    float* S2 = stats + (l*4+2)*2*DD;
    float* S3 = stats + (l*4+3)*2*DD;

    gather_k<<<NN/4, 256, 0, stream>>>(hb, row_ptr, slot, combo, t1);
    // t2 = t1 @ w1 + b1 ; stats S0
    mgemm_k<0,false,false,true><<<dim3(512,1), 512, 0, stream>>>(
        t1, nullptr, wl + 0, b1, nullptr,
        nullptr,nullptr,nullptr, nullptr,nullptr,nullptr, S0, t2, 256, 256);
    // t1 = relu( relu(bn(t2;S0,g1,be1)) @ w2 + b2 ) + hb ; stats S1
    mgemm_k<1,true,true,true><<<dim3(512,1), 512, 0, stream>>>(
        t2, nullptr, wl + 65536, b2, hb,
        S0, gine_g1 + l*DD, gine_be1 + l*DD, nullptr,nullptr,nullptr, S1, t1, 256, 256);
    // big = hb @ wqkv + bqkv
    mgemm_k<0,false,false,false><<<dim3(512,3), 512, 0, stream>>>(
        hb, nullptr, wl + 131072, bqkv, nullptr,
        nullptr,nullptr,nullptr, nullptr,nullptr,nullptr, nullptr, big, 768, 256);
    attn_k<<<GG*2, 256, 0, stream>>>(big, t2);
    // t4 = t2 @ wo + bo + hb ; stats S2
    mgemm_k<0,false,true,true><<<dim3(512,1), 512, 0, stream>>>(
        t2, nullptr, wl + 327680, bo, hb,
        nullptr,nullptr,nullptr, nullptr,nullptr,nullptr, S2, t4, 256, 256);
    // big = relu( (bn(t1;S1,n1)+bn(t4;S2,n2)) @ mw1 + mb1 )
    mgemm_k<2,true,false,false><<<dim3(512,2), 512, 0, stream>>>(
        t1, t4, wl + 393216, mb1, nullptr,
        S1, n1_g + l*DD, n1_b + l*DD, S2, n2_g + l*DD, n2_b + l*DD, nullptr, big, 512, 256);
    // hb = big @ mw2 + mb2 ; stats S3
    mgemm_k<0,false,false,true><<<dim3(512,1), 512, 0, stream>>>(
        big, nullptr, wl + 524288, mb2, nullptr,
        nullptr,nullptr,nullptr, nullptr,nullptr,nullptr, S3, hb, 256, 512);
    bnf_k<<<NN*DD/2048, 256, 0, stream>>>(hb, S3, n3_g + l*DD, n3_b + l*DD);
  }
  pool_k<<<GG, 256, 0, stream>>>(hb, out);
}